// Round 5
// baseline (108.795 us; speedup 1.0000x reference)
//
#include <hip/hip_runtime.h>
#include <math.h>

// B=2, N=512, DIM=512, HEADS=8, DIM_HEAD=64
// out[be,mu,z] = FFT1024(S_k*v)[mu] / FFT1024(k_)[mu],  mu in [0,512)
// after a 2x8 (b,h)-DFT; inputs zero-padded 512 -> 1024 on the m axis.
// GEMM path: split-bf16 MFMA (x=xh+xl, W=wh+wl; 3 MFMAs; residual ~2^-17).
// R12: fft as 3 register-fused radix-8 passes; twiddles hoisted to conv.
// R13 post-mortem: stage1->fft fusion regressed (axis-flip read amplification).
// R14: barrier-free FFT passes; sk folded into DFT; ushort4 conv stores.
// R15: gemm LDS-staged B via global_load_lds (dbuf, BK=64) -> -5.3us.
// R16 (this): Gk/Gp layout flipped to [be][z][m] — fft input loads become
// contiguous 4KB rows (was 64 scattered lines/wave); stage1 writes become
// scattered 8B stores (store-side scatter is free). gemm: A operands
// register-prefetched one K-step ahead (latency hidden under MFMA phase).
// mdft fallback updated for the new layout. All op orders preserved.

#define DIMX 512
#define NPOS 512
#define PADIDX(m) ((m) + ((m) >> 4))

typedef unsigned short ushort_t;
typedef unsigned int uint_t;
typedef __bf16 bf16x8 __attribute__((ext_vector_type(8)));
typedef float floatx4 __attribute__((ext_vector_type(4)));

static __device__ inline ushort_t f2bf(float f) {
    uint_t u = __float_as_uint(f);
    u = u + 0x7FFFu + ((u >> 16) & 1u);      // round-to-nearest-even
    return (ushort_t)(u >> 16);
}
static __device__ inline float bf2f(ushort_t h) {
    return __uint_as_float(((uint_t)h) << 16);
}

// butterfly: lo' = lo+hi; hi' = (lo-hi)*tw   (same op order as the original)
#define BFLY(lo, hi, tw) do {                                   \
    const float sr_ = (lo).x - (hi).x, si_ = (lo).y - (hi).y;   \
    (lo).x += (hi).x; (lo).y += (hi).y;                         \
    (hi).x = sr_ * (tw).x - si_ * (tw).y;                       \
    (hi).y = sr_ * (tw).y + si_ * (tw).x;                       \
} while (0)

// ---------------- conv (merged): blk<512 -> x split; blk<1024 -> W split+T;
// blk>=1024 -> FFT twiddle table (512 x double sincos, written once) --------
__global__ __launch_bounds__(256)
void conv_kernel(const float* __restrict__ x,
                 const float* __restrict__ Wk, const float* __restrict__ Wv,
                 ushort_t* __restrict__ xh, ushort_t* __restrict__ xl,
                 ushort_t* __restrict__ wth, ushort_t* __restrict__ wtl,
                 float2* __restrict__ twd)
{
    const int blk = blockIdx.x;
    const int t = threadIdx.x;
    if (blk < 512) {
        // x fp32 -> xh + xl, [m][k], one float4 per thread, ushort4 stores
        const int idx4 = blk * 256 + t;   // 131072 float4 groups
        const float4 v = ((const float4*)x)[idx4];
        const float vf[4] = {v.x, v.y, v.z, v.w};
        ushort_t h[4], l[4];
        #pragma unroll
        for (int e = 0; e < 4; ++e) {
            h[e] = f2bf(vf[e]);
            l[e] = f2bf(vf[e] - bf2f(h[e]));
        }
        const ushort4 hv4 = make_ushort4(h[0], h[1], h[2], h[3]);
        const ushort4 lv4 = make_ushort4(l[0], l[1], l[2], l[3]);
        *(ushort4*)(xh + (size_t)idx4 * 4) = hv4;
        *(ushort4*)(xl + (size_t)idx4 * 4) = lv4;
    } else if (blk < 1024) {
        // Wk|Wv [k][n] -> wth/wtl [n][k] split bf16, 32x32 LDS transpose
        __shared__ float tile[32][33];
        const int b2 = blk - 512;
        const int s  = b2 >> 8;            // 0=Wk, 1=Wv
        const int kt = (b2 >> 4) & 15;
        const int nt = b2 & 15;
        const int c  = t & 31, r4 = t >> 5;
        const float* __restrict__ W = s ? Wv : Wk;
        #pragma unroll
        for (int i = 0; i < 4; ++i) {
            const int row = r4 + i * 8;
            tile[row][c] = W[(size_t)(kt * 32 + row) * 512 + nt * 32 + c];
        }
        __syncthreads();
        #pragma unroll
        for (int i = 0; i < 4; ++i) {
            const int nl = r4 + i * 8;
            const float v = tile[c][nl];           // = W[kt*32+c][nt*32+nl]
            const ushort_t h = f2bf(v);
            const ushort_t l = f2bf(v - bf2f(h));
            const size_t o = (size_t)(s * 512 + nt * 32 + nl) * 512 + kt * 32 + c;
            wth[o] = h;
            wtl[o] = l;
        }
    } else {
        // twiddle table: exp(-2*pi*i*j/1024), j in [0,512)
        const int jj = (blk - 1024) * 256 + t;
        double s, cc;
        sincos(-6.2831853071795864769 * (double)jj / 1024.0, &s, &cc);
        twd[jj] = make_float2((float)cc, (float)s);
    }
}

// ---------------- GEMM: split-bf16 MFMA, LDS-staged B (global_load_lds) -----
// grid 512: ct = blk>>5 (16 col-tiles of 64), rt = blk&31 (32 row-tiles of 32);
// Wave w: rows rt*32+(w&1)*16, cols ct*64+(w>>1)*32 (2 col-frags) -> each B
// element staged ONCE per block. A operands register-prefetched one K-step
// ahead (R16): loads issue during MFMA phase, latency covered before the
// next barrier's vmcnt drain.
// B LDS layout [arr][kq=8][n=64][8 bf16]: gload_lds dest linear in lane order
// (m104); frag ds_read_b128 at n-stride 16 B -> 2-way bank alias (free, m136).
__global__ __launch_bounds__(256)
void gemm_mfma_kernel(const ushort_t* __restrict__ xh, const ushort_t* __restrict__ xl,
                      const ushort_t* __restrict__ wth, const ushort_t* __restrict__ wtl,
                      float* __restrict__ K, float* __restrict__ V,
                      float* __restrict__ partials)
{
    const int blk = blockIdx.x;       // 0..511
    const int ct = blk >> 5;          // 0..15
    const int rt = blk & 31;          // 0..31
    const int t = threadIdx.x;
    const int w = t >> 6, lane = t & 63;
    const int qd = lane >> 4, lm = lane & 15;

    const int mrow = rt * 32 + (w & 1) * 16 + lm;
    const int wcol = (w >> 1) * 32;                 // 0 or 32 within the 64-col tile
    const size_t aoff = (size_t)mrow * 512 + qd * 8;

    __shared__ __align__(16) ushort_t Bs[2][2][8][64][8];   // [buf][arr][kq][n][8k] = 32 KB
    __shared__ float red[4];

    // stage one BK=64 slab (16 KB) of B into LDS buffer `buf`:
    // 16 segments (arr x kq), 4 per wave; per segment: 64 lanes x 16 B, lane = n.
    #define STAGE(buf_, k0_)                                                     \
    {                                                                            \
        _Pragma("unroll")                                                        \
        for (int i = 0; i < 4; ++i) {                                            \
            const int seg = w * 4 + i;                                           \
            const int arr_ = seg >> 3, kq_ = seg & 7;                            \
            const ushort_t* src_ = (arr_ ? wtl : wth)                            \
                + (size_t)(ct * 64 + lane) * 512 + (k0_) + kq_ * 8;              \
            __builtin_amdgcn_global_load_lds(                                    \
                (const __attribute__((address_space(1))) uint_t*)src_,           \
                (__attribute__((address_space(3))) uint_t*)&Bs[buf_][arr_][kq_][0][0], \
                16, 0, 0);                                                       \
        }                                                                        \
    }

    floatx4 acc0 = {0.f, 0.f, 0.f, 0.f};
    floatx4 acc1 = {0.f, 0.f, 0.f, 0.f};

    // A register prefetch (current K-step operands)
    bf16x8 cAh0 = *(const bf16x8*)&xh[aoff];
    bf16x8 cAl0 = *(const bf16x8*)&xl[aoff];
    bf16x8 cAh1 = *(const bf16x8*)&xh[aoff + 32];
    bf16x8 cAl1 = *(const bf16x8*)&xl[aoff + 32];

    STAGE(0, 0)
    for (int ks = 0; ks < 8; ++ks) {
        __syncthreads();                       // drains gload_lds of buf[ks]
        const int buf = ks & 1;
        const int k0 = ks * 64;
        if (ks < 7) STAGE(buf ^ 1, k0 + 64)    // prefetch next slab async

        // issue next-step A loads now; consumed only after the next barrier
        const size_t anext = aoff + (size_t)(ks < 7 ? k0 + 64 : 0);
        const bf16x8 nAh0 = *(const bf16x8*)&xh[anext];
        const bf16x8 nAl0 = *(const bf16x8*)&xl[anext];
        const bf16x8 nAh1 = *(const bf16x8*)&xh[anext + 32];
        const bf16x8 nAl1 = *(const bf16x8*)&xl[anext + 32];

        // s2 = 0 (kq = qd)
        {
            const bf16x8 B0h = *(const bf16x8*)Bs[buf][0][qd][wcol + lm];
            const bf16x8 B0l = *(const bf16x8*)Bs[buf][1][qd][wcol + lm];
            const bf16x8 B1h = *(const bf16x8*)Bs[buf][0][qd][wcol + 16 + lm];
            const bf16x8 B1l = *(const bf16x8*)Bs[buf][1][qd][wcol + 16 + lm];
            acc0 = __builtin_amdgcn_mfma_f32_16x16x32_bf16(cAh0, B0h, acc0, 0, 0, 0);
            acc0 = __builtin_amdgcn_mfma_f32_16x16x32_bf16(cAh0, B0l, acc0, 0, 0, 0);
            acc0 = __builtin_amdgcn_mfma_f32_16x16x32_bf16(cAl0, B0h, acc0, 0, 0, 0);
            acc1 = __builtin_amdgcn_mfma_f32_16x16x32_bf16(cAh0, B1h, acc1, 0, 0, 0);
            acc1 = __builtin_amdgcn_mfma_f32_16x16x32_bf16(cAh0, B1l, acc1, 0, 0, 0);
            acc1 = __builtin_amdgcn_mfma_f32_16x16x32_bf16(cAl0, B1h, acc1, 0, 0, 0);
        }
        // s2 = 1 (kq = qd + 4)
        {
            const int kq = qd + 4;
            const bf16x8 B0h = *(const bf16x8*)Bs[buf][0][kq][wcol + lm];
            const bf16x8 B0l = *(const bf16x8*)Bs[buf][1][kq][wcol + lm];
            const bf16x8 B1h = *(const bf16x8*)Bs[buf][0][kq][wcol + 16 + lm];
            const bf16x8 B1l = *(const bf16x8*)Bs[buf][1][kq][wcol + 16 + lm];
            acc0 = __builtin_amdgcn_mfma_f32_16x16x32_bf16(cAh1, B0h, acc0, 0, 0, 0);
            acc0 = __builtin_amdgcn_mfma_f32_16x16x32_bf16(cAh1, B0l, acc0, 0, 0, 0);
            acc0 = __builtin_amdgcn_mfma_f32_16x16x32_bf16(cAl1, B0h, acc0, 0, 0, 0);
            acc1 = __builtin_amdgcn_mfma_f32_16x16x32_bf16(cAh1, B1h, acc1, 0, 0, 0);
            acc1 = __builtin_amdgcn_mfma_f32_16x16x32_bf16(cAh1, B1l, acc1, 0, 0, 0);
            acc1 = __builtin_amdgcn_mfma_f32_16x16x32_bf16(cAl1, B1h, acc1, 0, 0, 0);
        }
        cAh0 = nAh0; cAl0 = nAl0; cAh1 = nAh1; cAl1 = nAl1;
    }
    #undef STAGE

    // epilogue: D[row=quad*4+r][col=lane&15]
    float ss = 0.f;
    const int orow0 = rt * 32 + (w & 1) * 16 + qd * 4;
    float* __restrict__ O = (ct < 8) ? K : V;
    const int cb = (ct < 8) ? 0 : 512;
    const int c0 = ct * 64 + wcol + lm - cb;
    #pragma unroll
    for (int r = 0; r < 4; ++r) {
        const size_t row = orow0 + r;
        const float v0 = acc0[r], v1 = acc1[r];
        O[row * 512 + c0]      = v0;
        O[row * 512 + c0 + 16] = v1;
        if (ct < 8) ss += v0 * v0 + v1 * v1;
    }
    #pragma unroll
    for (int off = 32; off > 0; off >>= 1)
        ss += __shfl_down(ss, off, 64);
    if (lane == 0) red[w] = ss;
    __syncthreads();
    if (t == 0) partials[blk] = red[0] + red[1] + red[2] + red[3];
}

// 8-point DFT twiddles: exp(-2*pi*i*k/8)
__device__ __constant__ float C8[8] = {
    1.f, 0.70710678118654752440f, 0.f, -0.70710678118654752440f,
   -1.f, -0.70710678118654752440f, 0.f, 0.70710678118654752440f };
__device__ __constant__ float S8[8] = {
    0.f, -0.70710678118654752440f, -1.f, -0.70710678118654752440f,
    0.f,  0.70710678118654752440f,  1.f,  0.70710678118654752440f };

// elu(K/norm), S_k, P = S_k*V, 2x8 (b,h)-DFT.
// R16: writes Gk/Gp in [be][z=64][m=512] layout (m fastest) — scattered 8-B
// stores here buy fully-coalesced row reads in the fft kernel.
__global__ __launch_bounds__(256)
void stage1_kernel(const float* __restrict__ K,
                   const float* __restrict__ V,
                   const float* __restrict__ partials,
                   float2* __restrict__ Gk,
                   float2* __restrict__ Gp)
{
    const int m = blockIdx.x;     // 0..511
    const int t = threadIdx.x;
    __shared__ float kk[2][8][64];
    __shared__ float pp[2][8][64];
    __shared__ float skp[16][4];
    __shared__ float sk[2][8];
    __shared__ float sred[4];

    // reduce the 512 gemm partials -> global Frobenius scale
    float p = partials[t] + partials[t + 256];
    #pragma unroll
    for (int off = 32; off > 0; off >>= 1)
        p += __shfl_down(p, off, 64);
    if ((t & 63) == 0) sred[t >> 6] = p;
    __syncthreads();
    const float scale = (float)(1.0 / sqrt((double)sred[0] + (double)sred[1] +
                                           (double)sred[2] + (double)sred[3]));

    // float4 loads: thread t covers elements 4t..4t+3 (4 consecutive z)
    {
        const int e0 = t * 4;
        const int b = e0 >> 9, rem = e0 & 511, h = rem >> 6, z = rem & 63;
        const size_t src = (size_t)(b * 512 + m) * DIMX + h * 64 + z;
        const float4 kv4 = *(const float4*)&K[src];
        const float4 vv4 = *(const float4*)&V[src];
        const float kf[4] = {kv4.x, kv4.y, kv4.z, kv4.w};
        const float vf[4] = {vv4.x, vv4.y, vv4.z, vv4.w};
        #pragma unroll
        for (int e = 0; e < 4; ++e) {
            const float kv = kf[e] * scale;
            kk[b][h][z + e] = kv > 0.f ? kv : expm1f(kv);
            pp[b][h][z + e] = vf[e];
        }
    }
    __syncthreads();
    if (t < 64) {               // sk[b][h] = sum_z elu(k): 4 threads per (b,h)
        const int bh = t >> 2, q = t & 3;
        float s = 0.f;
        #pragma unroll
        for (int zz = 0; zz < 16; ++zz) s += kk[bh >> 3][bh & 7][q * 16 + zz];
        skp[bh][q] = s;
    }
    __syncthreads();
    if (t < 16) sk[t >> 3][t & 7] = skp[t][0] + skp[t][1] + skp[t][2] + skp[t][3];
    __syncthreads();

    // 2x8 (b,h)-DFT with folded sk; each thread computes a z-PAIR.
    for (int e2 = t; e2 < 512; e2 += 256) {
        const int be = e2 >> 5;          // 0..15
        const int zp = e2 & 31;          // z pair index
        const int beta = be >> 3, eta = be & 7;
        float kr[2] = {0.f, 0.f}, ki[2] = {0.f, 0.f};
        float pr[2] = {0.f, 0.f}, pim[2] = {0.f, 0.f};
        #pragma unroll
        for (int b = 0; b < 2; ++b) {
            const float sgn = (beta & b) ? -1.f : 1.f;
            #pragma unroll
            for (int h = 0; h < 8; ++h) {
                const int ph = (eta * h) & 7;
                const float cr = C8[ph], ci = S8[ph];
                const float skv = sk[b][h];
                #pragma unroll
                for (int zz = 0; zz < 2; ++zz) {
                    const int z = zp * 2 + zz;
                    const float a = kk[b][h][z] * sgn;
                    kr[zz] = fmaf(a, cr, kr[zz]);
                    ki[zz] = fmaf(a, ci, ki[zz]);
                    const float p2 = (pp[b][h][z] * skv) * sgn;
                    pr[zz]  = fmaf(p2, cr, pr[zz]);
                    pim[zz] = fmaf(p2, ci, pim[zz]);
                }
            }
        }
        // [be][z][m]: two consecutive z rows, column m
        const size_t rbase = ((size_t)be * 64 + zp * 2) * 512 + m;
        Gk[rbase]       = make_float2(kr[0], ki[0]);
        Gk[rbase + 512] = make_float2(kr[1], ki[1]);
        Gp[rbase]       = make_float2(pr[0], pim[0]);
        Gp[rbase + 512] = make_float2(pr[1], pim[1]);
    }
}

// ---------------- Zero-padded 1024-pt FFT (3 radix-8 passes) + divide -------
// R16: Gk/Gp are [be][z][m] (m fastest) -> each block reads 4 contiguous 4-KB
// rows, fully coalesced float4 loads. Zero-pad upper half not materialized;
// stage-0 twist fused into Pass A upper octet. FFT arrays wave-private
// between input and divide -> no mid-pass barriers.
__global__ __launch_bounds__(256)
void fft_div_kernel(const float2* __restrict__ Gk,   // [be][z][m]
                    const float2* __restrict__ Gp,
                    const float2* __restrict__ twd,  // 512 twiddles (from conv)
                    float* __restrict__ out, int out_cplx)
{
    const int blk = blockIdx.x;
    const int j  = blk & 7;
    const int l  = (blk >> 3) & 3;
    const int be = blk >> 5;
    const int zg = j * 4 + l;            // z = 2*zg, 2*zg+1
    const int t  = threadIdx.x;

    __shared__ float2 g[4][1088];   // arr = a*2+zi, padded 1024 -> 1088
    __shared__ float2 w[544];       // padded 512 twiddles

    // twiddle load + raw input load (lower 512 only), ONE barrier
    for (int jj = t; jj < 512; jj += 256)
        w[PADIDX(jj)] = twd[jj];
    for (int e = t; e < 1024; e += 256) {
        const int idx = e >> 8;          // 0:Gk z0, 1:Gk z1, 2:Gp z0, 3:Gp z1
        const int a  = idx >> 1, zi = idx & 1;
        const int m  = (e & 255) * 2;
        const float4 v4 = *(const float4*)&(a ? Gp : Gk)
            [((size_t)be * 64 + zg * 2 + zi) * 512 + m];
        g[a * 2 + zi][PADIDX(m)]     = make_float2(v4.x, v4.y);
        g[a * 2 + zi][PADIDX(m + 1)] = make_float2(v4.z, v4.w);
    }
    __syncthreads();

    const int wv   = t >> 6;
    const int lane = t & 63;

    // ---- Pass A: levels s=1..3, octets at stride 64 within each 512-half.
    // qh=0 -> upper half (reads lower raw + stage-0 twist), qh=1 -> lower.
    #pragma unroll
    for (int qh = 0; qh < 2; ++qh) {
        const int hh  = 1 - qh;
        const int arr = wv;
        const int jo  = lane;                // 0..63
        float2 f[8];
        #pragma unroll
        for (int k = 0; k < 8; ++k)
            f[k] = g[arr][PADIDX(jo + k * 64)];          // lower half (raw)
        if (hh == 1) {                                   // fused stage-0 twist
            #pragma unroll
            for (int k = 0; k < 8; ++k) {
                const float2 tw = w[PADIDX(jo + k * 64)];
                f[k] = make_float2(f[k].x * tw.x - f[k].y * tw.y,
                                   f[k].x * tw.y + f[k].y * tw.x);
            }
        }
        // s=1: pairs (k,k+4), twidx = 2*jo + 128*k
        #pragma unroll
        for (int k = 0; k < 4; ++k) {
            const float2 tw = w[PADIDX(2 * jo + 128 * k)];
            BFLY(f[k], f[k + 4], tw);
        }
        // s=2: pairs (k,k+2), twidx = 4*jo (+256 for odd k-lower)
        {
            const float2 tw0 = w[PADIDX(4 * jo)];
            const float2 tw1 = w[PADIDX(4 * jo + 256)];
            BFLY(f[0], f[2], tw0); BFLY(f[1], f[3], tw1);
            BFLY(f[4], f[6], tw0); BFLY(f[5], f[7], tw1);
        }
        // s=3: pairs (k,k+1), twidx = 8*jo
        {
            const float2 tw = w[PADIDX(8 * jo)];
            BFLY(f[0], f[1], tw); BFLY(f[2], f[3], tw);
            BFLY(f[4], f[5], tw); BFLY(f[6], f[7], tw);
        }
        #pragma unroll
        for (int k = 0; k < 8; ++k)
            g[arr][PADIDX(hh * 512 + jo + k * 64)] = f[k];
    }
    // wave-private array: no barrier needed (same-wave LDS program order)

    // ---- Pass B: levels s=4..6, octets at stride 8 within each 64-block.
    #pragma unroll
    for (int q = 0; q < 2; ++q) {
        const int arr = wv;
        const int b64 = q * 8 + (lane >> 3);   // 0..15
        const int jo  = lane & 7;              // 0..7
        const int e0  = b64 * 64 + jo;
        float2 f[8];
        #pragma unroll
        for (int k = 0; k < 8; ++k)
            f[k] = g[arr][PADIDX(e0 + 8 * k)];
        // s=4: pairs (k,k+4), twidx = 16*jo + 128*k
        #pragma unroll
        for (int k = 0; k < 4; ++k) {
            const float2 tw = w[PADIDX(16 * jo + 128 * k)];
            BFLY(f[k], f[k + 4], tw);
        }
        // s=5: pairs (k,k+2), twidx = 32*jo (+256)
        {
            const float2 tw0 = w[PADIDX(32 * jo)];
            const float2 tw1 = w[PADIDX(32 * jo + 256)];
            BFLY(f[0], f[2], tw0); BFLY(f[1], f[3], tw1);
            BFLY(f[4], f[6], tw0); BFLY(f[5], f[7], tw1);
        }
        // s=6: pairs (k,k+1), twidx = 64*jo
        {
            const float2 tw = w[PADIDX(64 * jo)];
            BFLY(f[0], f[1], tw); BFLY(f[2], f[3], tw);
            BFLY(f[4], f[5], tw); BFLY(f[6], f[7], tw);
        }
        #pragma unroll
        for (int k = 0; k < 8; ++k)
            g[arr][PADIDX(e0 + 8 * k)] = f[k];
    }
    // wave-private array: no barrier needed

    // ---- Pass C: levels s=7..9, consecutive 8-blocks. Level 9 keeps only
    // even positions (odd outputs are never read by the divide).
    #pragma unroll
    for (int q = 0; q < 2; ++q) {
        const int arr = wv;
        const int b8  = q * 64 + lane;       // 0..127
        const int e0  = b8 * 8;
        float2 f[8];
        #pragma unroll
        for (int k = 0; k < 8; ++k)
            f[k] = g[arr][PADIDX(e0 + k)];
        // s=7: pairs (k,k+4), twidx = 128*k
        BFLY(f[0], f[4], w[PADIDX(0)]);
        BFLY(f[1], f[5], w[PADIDX(128)]);
        BFLY(f[2], f[6], w[PADIDX(256)]);
        BFLY(f[3], f[7], w[PADIDX(384)]);
        // s=8: pairs (k,k+2), twidx = 256*(k&1)
        {
            const float2 tw0 = w[PADIDX(0)];
            const float2 tw1 = w[PADIDX(256)];
            BFLY(f[0], f[2], tw0); BFLY(f[1], f[3], tw1);
            BFLY(f[4], f[6], tw0); BFLY(f[5], f[7], tw1);
        }
        // s=9: evens only: f[k] += f[k+1]
        f[0].x += f[1].x; f[0].y += f[1].y;
        f[2].x += f[3].x; f[2].y += f[3].y;
        f[4].x += f[5].x; f[4].y += f[5].y;
        f[6].x += f[7].x; f[6].y += f[7].y;
        g[arr][PADIDX(e0 + 0)] = f[0];
        g[arr][PADIDX(e0 + 2)] = f[2];
        g[arr][PADIDX(e0 + 4)] = f[4];
        g[arr][PADIDX(e0 + 6)] = f[6];
    }
    __syncthreads();

    // even positions 2i hold mu = bitrev9(i). Divide both z and store float4.
    for (int e2 = t; e2 < 512; e2 += 256) {
        const int i  = e2;
        const int pi = PADIDX(2 * i);
        const int mu = (int)(__brev((unsigned)i) >> 23);   // bitrev9
        float4 res;
        #pragma unroll
        for (int zi = 0; zi < 2; ++zi) {
            const float2 D  = g[zi][pi];
            const float2 Nm = g[2 + zi][pi];
            const float inv = 1.f / (D.x * D.x + D.y * D.y);
            const float rr = (Nm.x * D.x + Nm.y * D.y) * inv;
            const float ri = (Nm.y * D.x - Nm.x * D.y) * inv;
            if (zi == 0) { res.x = rr; res.y = ri; }
            else         { res.z = rr; res.w = ri; }
        }
        const size_t o = ((size_t)be * NPOS + mu) * 64 + zg * 2;
        if (out_cplx) {
            *(float4*)&((float2*)out)[o] = res;
        } else {
            out[o]     = res.x;
            out[o + 1] = res.z;
        }
    }
}

// ---------------- small-ws fallback: fp32 GEMM + fp64 mdft ------------------
__global__ __launch_bounds__(256)
void gemm_kv_kernel(const float* __restrict__ x,
                    const float* __restrict__ Wk,
                    const float* __restrict__ Wv,
                    float* __restrict__ K,
                    float* __restrict__ V,
                    float* __restrict__ partials)
{
    const int blk  = blockIdx.x;
    const int sel  = (blk >> 2) & 1;
    const int cg2  = blk & 3;
    const int rt   = blk >> 3;
    const int row0 = rt * 16;
    const int col0 = cg2 * 128;
    const int t    = threadIdx.x;
    const int tc   = t & 31;
    const int tr   = t >> 5;
    const float* __restrict__ W   = sel ? Wv : Wk;
    float* __restrict__       Out = sel ? V  : K;

    __shared__ float xs[16][DIMX];
    __shared__ float red[4];

    #pragma unroll
    for (int jj = 0; jj < 8; ++jj) {
        const int f = t + jj * 256;
        const int row = f >> 7, c4 = f & 127;
        *(float4*)&xs[row][c4 * 4] = *(const float4*)&x[(size_t)(row0 + row) * DIMX + c4 * 4];
    }
    __syncthreads();

    const float* Wb = W + col0 + tc * 4;
    float4 wA[8], wB[8];
    #pragma unroll
    for (int jj = 0; jj < 8; ++jj) wA[jj] = *(const float4*)&Wb[(size_t)(jj) * DIMX];
    #pragma unroll
    for (int jj = 0; jj < 8; ++jj) wB[jj] = *(const float4*)&Wb[(size_t)(8 + jj) * DIMX];

    float acc[2][4] = {{0,0,0,0},{0,0,0,0}};
    const int r0 = tr * 2;

    #define COMPUTE_CHUNK(WREG, CH)                                            \
        {   float4 xv0a = *(const float4*)&xs[r0][(CH) * 8];                   \
            float4 xv0b = *(const float4*)&xs[r0][(CH) * 8 + 4];               \
            float4 xv1a = *(const float4*)&xs[r0 + 1][(CH) * 8];               \
            float4 xv1b = *(const float4*)&xs[r0 + 1][(CH) * 8 + 4];           \
            _Pragma("unroll")                                                  \
            for (int kk = 0; kk < 4; ++kk) {                                   \
                const float x0 = (&xv0a.x)[kk], x1 = (&xv1a.x)[kk];            \
                _Pragma("unroll")                                              \
                for (int cc = 0; cc < 4; ++cc) {                               \
                    acc[0][cc] = fmaf(x0, (&WREG[kk].x)[cc], acc[0][cc]);      \
                    acc[1][cc] = fmaf(x1, (&WREG[kk].x)[cc], acc[1][cc]);      \
                } }                                                            \
            _Pragma("unroll")                                                  \
            for (int kk = 0; kk < 4; ++kk) {                                   \
                const float x0 = (&xv0b.x)[kk], x1 = (&xv1b.x)[kk];            \
                _Pragma("unroll")                                              \
                for (int cc = 0; cc < 4; ++cc) {                               \
                    acc[0][cc] = fmaf(x0, (&WREG[kk + 4].x)[cc], acc[0][cc]);  \
                    acc[1][cc] = fmaf(x1, (&WREG[kk + 4].x)[cc], acc[1][cc]);  \
                } } }

    for (int ch = 0; ch < 64; ch += 2) {
        COMPUTE_CHUNK(wA, ch)
        if (ch < 62) {
            #pragma unroll
            for (int jj = 0; jj < 8; ++jj)
                wA[jj] = *(const float4*)&Wb[(size_t)((ch + 2) * 8 + jj) * DIMX];
        }
        COMPUTE_CHUNK(wB, ch + 1)
        if (ch < 62) {
            #pragma unroll
            for (int jj = 0; jj < 8; ++jj)
                wB[jj] = *(const float4*)&Wb[(size_t)((ch + 3) * 8 + jj) * DIMX];
        }
    }
    #undef COMPUTE_CHUNK

    float ss = 0.f;
    #pragma unroll
    for (int i = 0; i < 2; ++i) {
        const int row = row0 + r0 + i;
        const float4 o = make_float4(acc[i][0], acc[i][1], acc[i][2], acc[i][3]);
        *(float4*)&Out[(size_t)row * DIMX + col0 + tc * 4] = o;
        ss += o.x * o.x + o.y * o.y + o.z * o.z + o.w * o.w;
    }
    if (sel == 0) {
        #pragma unroll
        for (int off = 32; off > 0; off >>= 1)
            ss += __shfl_down(ss, off, 64);
        if ((t & 63) == 0) red[t >> 6] = ss;
        __syncthreads();
        if (t == 0) partials[blk] = red[0] + red[1] + red[2] + red[3];
    } else {
        if (t == 0) partials[blk] = 0.f;
    }
}

__global__ __launch_bounds__(256)
void mdft_fallback_kernel(const float2* __restrict__ Gk,  // [be][z][m]
                          const float2* __restrict__ Gp,
                          float* __restrict__ out,
                          int out_cplx)
{
    const int blk = blockIdx.x;
    const int be = blk >> 6, z = blk & 63;
    const int t = threadIdx.x;
    __shared__ float2 gk[512];
    __shared__ float2 gp[512];
    __shared__ float2 w[1024];

    for (int m = t; m < 512; m += 256) {
        const size_t idx = ((size_t)be * 64 + z) * 512 + m;
        gk[m] = Gk[idx];
        gp[m] = Gp[idx];
    }
    for (int jj = t; jj < 1024; jj += 256) {
        double s, c;
        sincos(-6.2831853071795864769 * (double)jj / 1024.0, &s, &c);
        w[jj] = make_float2((float)c, (float)s);
    }
    __syncthreads();

    #pragma unroll
    for (int half = 0; half < 2; ++half) {
        const int mu = t + half * 256;
        double dr = 0.0, di = 0.0, nr = 0.0, ni = 0.0;
        int idx = 0;
        for (int m = 0; m < 512; ++m) {
            const float2 tw = w[idx];
            idx = (idx + mu) & 1023;
            const float2 a = gk[m];
            dr += (double)(a.x * tw.x - a.y * tw.y);
            di += (double)(a.x * tw.y + a.y * tw.x);
            const float2 p2 = gp[m];
            nr += (double)(p2.x * tw.x - p2.y * tw.y);
            ni += (double)(p2.x * tw.y + p2.y * tw.x);
        }
        const double dmag = dr * dr + di * di;
        const double orr = (nr * dr + ni * di) / dmag;
        const double oii = (ni * dr - nr * di) / dmag;
        const size_t o = ((size_t)be * NPOS + mu) * 64 + z;
        if (out_cplx) {
            out[2 * o]     = (float)orr;
            out[2 * o + 1] = (float)oii;
        } else {
            out[o] = (float)orr;
        }
    }
}

extern "C" void kernel_launch(void* const* d_in, const int* in_sizes, int n_in,
                              void* d_out, int out_size, void* d_ws, size_t ws_size,
                              hipStream_t stream)
{
    // inputs: x, Wq, Wk, Wv, Er — only x, Wk, Wv needed
    const float* x  = (const float*)d_in[0];
    const float* Wk = (const float*)d_in[2];
    const float* Wv = (const float*)d_in[3];
    float* out = (float*)d_out;

    char* ws = (char*)d_ws;
    float*  K    = (float*)(ws);                           // 2 MB
    float*  V    = (float*)(ws + (size_t)2097152);         // 2 MB
    float2* Gk   = (float2*)(ws + (size_t)4194304);        // 4 MB
    float*  part = (float*)(ws + (size_t)8388608);         // 2 KB (512 floats)
    const int out_cplx = (out_size >= 2 * 2 * 8 * 512 * 64) ? 1 : 0;

    const bool ws_big = (ws_size >= (size_t)20971520);     // needs 20 MB
    float2* Gp = ws_big ? (float2*)(ws + (size_t)8390656)  // 4 MB
                        : (float2*)d_out;                  // alias-safe fallback

    if (ws_big) {
        ushort_t* xh  = (ushort_t*)(ws + (size_t)16777216);  // 1 MB each
        ushort_t* xl  = (ushort_t*)(ws + (size_t)17825792);
        ushort_t* wth = (ushort_t*)(ws + (size_t)18874368);
        ushort_t* wtl = (ushort_t*)(ws + (size_t)19922944);
        float2*   twd = (float2*)(ws + (size_t)12584960);    // 4 KB (hole after Gp)
        hipLaunchKernelGGL(conv_kernel, dim3(1026), dim3(256), 0, stream,
                           x, Wk, Wv, xh, xl, wth, wtl, twd);
        hipLaunchKernelGGL(gemm_mfma_kernel, dim3(512), dim3(256), 0, stream,
                           xh, xl, wth, wtl, K, V, part);
        hipLaunchKernelGGL(stage1_kernel, dim3(512), dim3(256), 0, stream,
                           K, V, part, Gk, Gp);
        hipLaunchKernelGGL(fft_div_kernel, dim3(512), dim3(256), 0, stream,
                           Gk, Gp, twd, out, out_cplx);
    } else {
        hipLaunchKernelGGL(gemm_kv_kernel, dim3(512), dim3(256), 0, stream,
                           x, Wk, Wv, K, V, part);
        hipLaunchKernelGGL(stage1_kernel, dim3(512), dim3(256), 0, stream,
                           K, V, part, Gk, Gp);
        hipLaunchKernelGGL(mdft_fallback_kernel, dim3(1024), dim3(256), 0, stream,
                           Gk, Gp, out, out_cplx);
    }
}

// Round 6
// 99.054 us; speedup vs baseline: 1.0983x; 1.0983x over previous
//
#include <hip/hip_runtime.h>
#include <math.h>

// B=2, N=512, DIM=512, HEADS=8, DIM_HEAD=64
// out[be,mu,z] = FFT1024(S_k*v)[mu] / FFT1024(k_)[mu],  mu in [0,512)
// after a 2x8 (b,h)-DFT; inputs zero-padded 512 -> 1024 on the m axis.
// Gk/Gp layout: [be][m][z] (z fastest) — PRODUCER-coalesced. R16 tried
// [be][z][m] (consumer-coalesced): +8.7us REGRESSION — m is stage1's
// blockIdx, so each 64B line got 8B fragments from 8 different workgroups
// (cross-XCD false sharing, partial-line RFO). Scatter must live on the
// READ side (L2-hot, same-XCD block swizzle). Do not revisit.
// GEMM path: split-bf16 MFMA (x=xh+xl, W=wh+wl; 3 MFMAs; residual ~2^-17).
// R12: fft as 3 register-fused radix-8 passes; twiddles hoisted to conv.
// R14: barrier-free FFT passes; sk folded into DFT; ushort4 conv stores.
// R15: gemm LDS-staged B via global_load_lds (dbuf, BK=64) -> -5.3us.
// R17 (this): R15 structure + gemm A-operand register prefetch (loads issue
// under the MFMA phase, latency covered before the next barrier drain).

#define DIMX 512
#define NPOS 512
#define PADIDX(m) ((m) + ((m) >> 4))

typedef unsigned short ushort_t;
typedef unsigned int uint_t;
typedef __bf16 bf16x8 __attribute__((ext_vector_type(8)));
typedef float floatx4 __attribute__((ext_vector_type(4)));

static __device__ inline ushort_t f2bf(float f) {
    uint_t u = __float_as_uint(f);
    u = u + 0x7FFFu + ((u >> 16) & 1u);      // round-to-nearest-even
    return (ushort_t)(u >> 16);
}
static __device__ inline float bf2f(ushort_t h) {
    return __uint_as_float(((uint_t)h) << 16);
}

// butterfly: lo' = lo+hi; hi' = (lo-hi)*tw   (same op order as the original)
#define BFLY(lo, hi, tw) do {                                   \
    const float sr_ = (lo).x - (hi).x, si_ = (lo).y - (hi).y;   \
    (lo).x += (hi).x; (lo).y += (hi).y;                         \
    (hi).x = sr_ * (tw).x - si_ * (tw).y;                       \
    (hi).y = sr_ * (tw).y + si_ * (tw).x;                       \
} while (0)

// ---------------- conv (merged): blk<512 -> x split; blk<1024 -> W split+T;
// blk>=1024 -> FFT twiddle table (512 x double sincos, written once) --------
__global__ __launch_bounds__(256)
void conv_kernel(const float* __restrict__ x,
                 const float* __restrict__ Wk, const float* __restrict__ Wv,
                 ushort_t* __restrict__ xh, ushort_t* __restrict__ xl,
                 ushort_t* __restrict__ wth, ushort_t* __restrict__ wtl,
                 float2* __restrict__ twd)
{
    const int blk = blockIdx.x;
    const int t = threadIdx.x;
    if (blk < 512) {
        // x fp32 -> xh + xl, [m][k], one float4 per thread, ushort4 stores
        const int idx4 = blk * 256 + t;   // 131072 float4 groups
        const float4 v = ((const float4*)x)[idx4];
        const float vf[4] = {v.x, v.y, v.z, v.w};
        ushort_t h[4], l[4];
        #pragma unroll
        for (int e = 0; e < 4; ++e) {
            h[e] = f2bf(vf[e]);
            l[e] = f2bf(vf[e] - bf2f(h[e]));
        }
        const ushort4 hv4 = make_ushort4(h[0], h[1], h[2], h[3]);
        const ushort4 lv4 = make_ushort4(l[0], l[1], l[2], l[3]);
        *(ushort4*)(xh + (size_t)idx4 * 4) = hv4;
        *(ushort4*)(xl + (size_t)idx4 * 4) = lv4;
    } else if (blk < 1024) {
        // Wk|Wv [k][n] -> wth/wtl [n][k] split bf16, 32x32 LDS transpose
        __shared__ float tile[32][33];
        const int b2 = blk - 512;
        const int s  = b2 >> 8;            // 0=Wk, 1=Wv
        const int kt = (b2 >> 4) & 15;
        const int nt = b2 & 15;
        const int c  = t & 31, r4 = t >> 5;
        const float* __restrict__ W = s ? Wv : Wk;
        #pragma unroll
        for (int i = 0; i < 4; ++i) {
            const int row = r4 + i * 8;
            tile[row][c] = W[(size_t)(kt * 32 + row) * 512 + nt * 32 + c];
        }
        __syncthreads();
        #pragma unroll
        for (int i = 0; i < 4; ++i) {
            const int nl = r4 + i * 8;
            const float v = tile[c][nl];           // = W[kt*32+c][nt*32+nl]
            const ushort_t h = f2bf(v);
            const ushort_t l = f2bf(v - bf2f(h));
            const size_t o = (size_t)(s * 512 + nt * 32 + nl) * 512 + kt * 32 + c;
            wth[o] = h;
            wtl[o] = l;
        }
    } else {
        // twiddle table: exp(-2*pi*i*j/1024), j in [0,512)
        const int jj = (blk - 1024) * 256 + t;
        double s, cc;
        sincos(-6.2831853071795864769 * (double)jj / 1024.0, &s, &cc);
        twd[jj] = make_float2((float)cc, (float)s);
    }
}

// ---------------- GEMM: split-bf16 MFMA, LDS-staged B (global_load_lds) -----
// grid 512: ct = blk>>5 (16 col-tiles of 64), rt = blk&31 (32 row-tiles of 32);
// Wave w: rows rt*32+(w&1)*16, cols ct*64+(w>>1)*32 (2 col-frags) -> each B
// element staged ONCE per block. A operands register-prefetched one K-step
// ahead (R17): loads issue during MFMA phase, latency covered before the
// next barrier's vmcnt drain.
// B LDS layout [arr][kq=8][n=64][8 bf16]: gload_lds dest linear in lane order
// (m104); frag ds_read_b128 at n-stride 16 B -> 2-way bank alias (free, m136).
__global__ __launch_bounds__(256)
void gemm_mfma_kernel(const ushort_t* __restrict__ xh, const ushort_t* __restrict__ xl,
                      const ushort_t* __restrict__ wth, const ushort_t* __restrict__ wtl,
                      float* __restrict__ K, float* __restrict__ V,
                      float* __restrict__ partials)
{
    const int blk = blockIdx.x;       // 0..511
    const int ct = blk >> 5;          // 0..15
    const int rt = blk & 31;          // 0..31
    const int t = threadIdx.x;
    const int w = t >> 6, lane = t & 63;
    const int qd = lane >> 4, lm = lane & 15;

    const int mrow = rt * 32 + (w & 1) * 16 + lm;
    const int wcol = (w >> 1) * 32;                 // 0 or 32 within the 64-col tile
    const size_t aoff = (size_t)mrow * 512 + qd * 8;

    __shared__ __align__(16) ushort_t Bs[2][2][8][64][8];   // [buf][arr][kq][n][8k] = 32 KB
    __shared__ float red[4];

    // stage one BK=64 slab (16 KB) of B into LDS buffer `buf`:
    // 16 segments (arr x kq), 4 per wave; per segment: 64 lanes x 16 B, lane = n.
    #define STAGE(buf_, k0_)                                                     \
    {                                                                            \
        _Pragma("unroll")                                                        \
        for (int i = 0; i < 4; ++i) {                                            \
            const int seg = w * 4 + i;                                           \
            const int arr_ = seg >> 3, kq_ = seg & 7;                            \
            const ushort_t* src_ = (arr_ ? wtl : wth)                            \
                + (size_t)(ct * 64 + lane) * 512 + (k0_) + kq_ * 8;              \
            __builtin_amdgcn_global_load_lds(                                    \
                (const __attribute__((address_space(1))) uint_t*)src_,           \
                (__attribute__((address_space(3))) uint_t*)&Bs[buf_][arr_][kq_][0][0], \
                16, 0, 0);                                                       \
        }                                                                        \
    }

    floatx4 acc0 = {0.f, 0.f, 0.f, 0.f};
    floatx4 acc1 = {0.f, 0.f, 0.f, 0.f};

    // A register prefetch (current K-step operands)
    bf16x8 cAh0 = *(const bf16x8*)&xh[aoff];
    bf16x8 cAl0 = *(const bf16x8*)&xl[aoff];
    bf16x8 cAh1 = *(const bf16x8*)&xh[aoff + 32];
    bf16x8 cAl1 = *(const bf16x8*)&xl[aoff + 32];

    STAGE(0, 0)
    for (int ks = 0; ks < 8; ++ks) {
        __syncthreads();                       // drains gload_lds of buf[ks]
        const int buf = ks & 1;
        const int k0 = ks * 64;
        if (ks < 7) STAGE(buf ^ 1, k0 + 64)    // prefetch next slab async

        // issue next-step A loads now; consumed only after the next barrier
        const size_t anext = aoff + (size_t)(ks < 7 ? k0 + 64 : 0);
        const bf16x8 nAh0 = *(const bf16x8*)&xh[anext];
        const bf16x8 nAl0 = *(const bf16x8*)&xl[anext];
        const bf16x8 nAh1 = *(const bf16x8*)&xh[anext + 32];
        const bf16x8 nAl1 = *(const bf16x8*)&xl[anext + 32];

        // s2 = 0 (kq = qd)
        {
            const bf16x8 B0h = *(const bf16x8*)Bs[buf][0][qd][wcol + lm];
            const bf16x8 B0l = *(const bf16x8*)Bs[buf][1][qd][wcol + lm];
            const bf16x8 B1h = *(const bf16x8*)Bs[buf][0][qd][wcol + 16 + lm];
            const bf16x8 B1l = *(const bf16x8*)Bs[buf][1][qd][wcol + 16 + lm];
            acc0 = __builtin_amdgcn_mfma_f32_16x16x32_bf16(cAh0, B0h, acc0, 0, 0, 0);
            acc0 = __builtin_amdgcn_mfma_f32_16x16x32_bf16(cAh0, B0l, acc0, 0, 0, 0);
            acc0 = __builtin_amdgcn_mfma_f32_16x16x32_bf16(cAl0, B0h, acc0, 0, 0, 0);
            acc1 = __builtin_amdgcn_mfma_f32_16x16x32_bf16(cAh0, B1h, acc1, 0, 0, 0);
            acc1 = __builtin_amdgcn_mfma_f32_16x16x32_bf16(cAh0, B1l, acc1, 0, 0, 0);
            acc1 = __builtin_amdgcn_mfma_f32_16x16x32_bf16(cAl0, B1h, acc1, 0, 0, 0);
        }
        // s2 = 1 (kq = qd + 4)
        {
            const int kq = qd + 4;
            const bf16x8 B0h = *(const bf16x8*)Bs[buf][0][kq][wcol + lm];
            const bf16x8 B0l = *(const bf16x8*)Bs[buf][1][kq][wcol + lm];
            const bf16x8 B1h = *(const bf16x8*)Bs[buf][0][kq][wcol + 16 + lm];
            const bf16x8 B1l = *(const bf16x8*)Bs[buf][1][kq][wcol + 16 + lm];
            acc0 = __builtin_amdgcn_mfma_f32_16x16x32_bf16(cAh1, B0h, acc0, 0, 0, 0);
            acc0 = __builtin_amdgcn_mfma_f32_16x16x32_bf16(cAh1, B0l, acc0, 0, 0, 0);
            acc0 = __builtin_amdgcn_mfma_f32_16x16x32_bf16(cAl1, B0h, acc0, 0, 0, 0);
            acc1 = __builtin_amdgcn_mfma_f32_16x16x32_bf16(cAh1, B1h, acc1, 0, 0, 0);
            acc1 = __builtin_amdgcn_mfma_f32_16x16x32_bf16(cAh1, B1l, acc1, 0, 0, 0);
            acc1 = __builtin_amdgcn_mfma_f32_16x16x32_bf16(cAl1, B1h, acc1, 0, 0, 0);
        }
        cAh0 = nAh0; cAl0 = nAl0; cAh1 = nAh1; cAl1 = nAl1;
    }
    #undef STAGE

    // epilogue: D[row=quad*4+r][col=lane&15]
    float ss = 0.f;
    const int orow0 = rt * 32 + (w & 1) * 16 + qd * 4;
    float* __restrict__ O = (ct < 8) ? K : V;
    const int cb = (ct < 8) ? 0 : 512;
    const int c0 = ct * 64 + wcol + lm - cb;
    #pragma unroll
    for (int r = 0; r < 4; ++r) {
        const size_t row = orow0 + r;
        const float v0 = acc0[r], v1 = acc1[r];
        O[row * 512 + c0]      = v0;
        O[row * 512 + c0 + 16] = v1;
        if (ct < 8) ss += v0 * v0 + v1 * v1;
    }
    #pragma unroll
    for (int off = 32; off > 0; off >>= 1)
        ss += __shfl_down(ss, off, 64);
    if (lane == 0) red[w] = ss;
    __syncthreads();
    if (t == 0) partials[blk] = red[0] + red[1] + red[2] + red[3];
}

// 8-point DFT twiddles: exp(-2*pi*i*k/8)
__device__ __constant__ float C8[8] = {
    1.f, 0.70710678118654752440f, 0.f, -0.70710678118654752440f,
   -1.f, -0.70710678118654752440f, 0.f, 0.70710678118654752440f };
__device__ __constant__ float S8[8] = {
    0.f, -0.70710678118654752440f, -1.f, -0.70710678118654752440f,
    0.f,  0.70710678118654752440f,  1.f,  0.70710678118654752440f };

// elu(K/norm), S_k, P = S_k*V, 2x8 (b,h)-DFT. Writes [be][m][z], float4
// (producer-coalesced full-line stores; consumer scatter is the cheap side).
__global__ __launch_bounds__(256)
void stage1_kernel(const float* __restrict__ K,
                   const float* __restrict__ V,
                   const float* __restrict__ partials,
                   float2* __restrict__ Gk,
                   float2* __restrict__ Gp)
{
    const int m = blockIdx.x;     // 0..511
    const int t = threadIdx.x;
    __shared__ float kk[2][8][64];
    __shared__ float pp[2][8][64];
    __shared__ float skp[16][4];
    __shared__ float sk[2][8];
    __shared__ float sred[4];

    // reduce the 512 gemm partials -> global Frobenius scale
    float p = partials[t] + partials[t + 256];
    #pragma unroll
    for (int off = 32; off > 0; off >>= 1)
        p += __shfl_down(p, off, 64);
    if ((t & 63) == 0) sred[t >> 6] = p;
    __syncthreads();
    const float scale = (float)(1.0 / sqrt((double)sred[0] + (double)sred[1] +
                                           (double)sred[2] + (double)sred[3]));

    // float4 loads: thread t covers elements 4t..4t+3 (4 consecutive z)
    {
        const int e0 = t * 4;
        const int b = e0 >> 9, rem = e0 & 511, h = rem >> 6, z = rem & 63;
        const size_t src = (size_t)(b * 512 + m) * DIMX + h * 64 + z;
        const float4 kv4 = *(const float4*)&K[src];
        const float4 vv4 = *(const float4*)&V[src];
        const float kf[4] = {kv4.x, kv4.y, kv4.z, kv4.w};
        const float vf[4] = {vv4.x, vv4.y, vv4.z, vv4.w};
        #pragma unroll
        for (int e = 0; e < 4; ++e) {
            const float kv = kf[e] * scale;
            kk[b][h][z + e] = kv > 0.f ? kv : expm1f(kv);
            pp[b][h][z + e] = vf[e];
        }
    }
    __syncthreads();
    if (t < 64) {               // sk[b][h] = sum_z elu(k): 4 threads per (b,h)
        const int bh = t >> 2, q = t & 3;
        float s = 0.f;
        #pragma unroll
        for (int zz = 0; zz < 16; ++zz) s += kk[bh >> 3][bh & 7][q * 16 + zz];
        skp[bh][q] = s;
    }
    __syncthreads();
    if (t < 16) sk[t >> 3][t & 7] = skp[t][0] + skp[t][1] + skp[t][2] + skp[t][3];
    __syncthreads();

    // 2x8 (b,h)-DFT with folded sk; each thread computes a z-PAIR -> float4.
    for (int e2 = t; e2 < 512; e2 += 256) {
        const int be = e2 >> 5;          // 0..15
        const int zp = e2 & 31;          // z pair index
        const int beta = be >> 3, eta = be & 7;
        float kr[2] = {0.f, 0.f}, ki[2] = {0.f, 0.f};
        float pr[2] = {0.f, 0.f}, pim[2] = {0.f, 0.f};
        #pragma unroll
        for (int b = 0; b < 2; ++b) {
            const float sgn = (beta & b) ? -1.f : 1.f;
            #pragma unroll
            for (int h = 0; h < 8; ++h) {
                const int ph = (eta * h) & 7;
                const float cr = C8[ph], ci = S8[ph];
                const float skv = sk[b][h];
                #pragma unroll
                for (int zz = 0; zz < 2; ++zz) {
                    const int z = zp * 2 + zz;
                    const float a = kk[b][h][z] * sgn;
                    kr[zz] = fmaf(a, cr, kr[zz]);
                    ki[zz] = fmaf(a, ci, ki[zz]);
                    const float p2 = (pp[b][h][z] * skv) * sgn;
                    pr[zz]  = fmaf(p2, cr, pr[zz]);
                    pim[zz] = fmaf(p2, ci, pim[zz]);
                }
            }
        }
        const float4 rk = make_float4(kr[0], ki[0], kr[1], ki[1]);
        const float4 rp = make_float4(pr[0], pim[0], pr[1], pim[1]);
        const size_t o = ((size_t)be * NPOS + m) * 64 + zp * 2;
        *(float4*)&Gk[o] = rk;
        *(float4*)&Gp[o] = rp;
    }
}

// ---------------- Zero-padded 1024-pt FFT (3 radix-8 passes) + divide -------
// Swizzle: blk = be*32 + l*8 + j, zg = j*4 + l  ->  the 4 blocks sharing each
// 64B out-line / Gk-line (zg group of 4, fixed be) have equal blk%8 (same XCD).
// Zero-pad upper half not materialized; stage-0 twist fused into Pass A upper
// octet. FFT arrays wave-private between input and divide -> no mid barriers.
__global__ __launch_bounds__(256)
void fft_div_kernel(const float2* __restrict__ Gk,   // [be][m][z]
                    const float2* __restrict__ Gp,
                    const float2* __restrict__ twd,  // 512 twiddles (from conv)
                    float* __restrict__ out, int out_cplx)
{
    const int blk = blockIdx.x;
    const int j  = blk & 7;
    const int l  = (blk >> 3) & 3;
    const int be = blk >> 5;
    const int zg = j * 4 + l;            // z = 2*zg, 2*zg+1
    const int t  = threadIdx.x;

    __shared__ float2 g[4][1088];   // arr = a*2+zi, padded 1024 -> 1088
    __shared__ float2 w[544];       // padded 512 twiddles

    // twiddle load + raw input load (lower 512 only), ONE barrier
    for (int jj = t; jj < 512; jj += 256)
        w[PADIDX(jj)] = twd[jj];
    for (int e = t; e < 1024; e += 256) {
        const int a = e >> 9;            // 0 -> Gk, 1 -> Gp
        const int m = e & 511;
        const float4 v4 = *(const float4*)&(a ? Gp : Gk)[((size_t)be * NPOS + m) * 64 + zg * 2];
        g[a * 2 + 0][PADIDX(m)] = make_float2(v4.x, v4.y);
        g[a * 2 + 1][PADIDX(m)] = make_float2(v4.z, v4.w);
    }
    __syncthreads();

    const int wv   = t >> 6;
    const int lane = t & 63;

    // ---- Pass A: levels s=1..3, octets at stride 64 within each 512-half.
    // qh=0 -> upper half (reads lower raw + stage-0 twist), qh=1 -> lower.
    #pragma unroll
    for (int qh = 0; qh < 2; ++qh) {
        const int hh  = 1 - qh;
        const int arr = wv;
        const int jo  = lane;                // 0..63
        float2 f[8];
        #pragma unroll
        for (int k = 0; k < 8; ++k)
            f[k] = g[arr][PADIDX(jo + k * 64)];          // lower half (raw)
        if (hh == 1) {                                   // fused stage-0 twist
            #pragma unroll
            for (int k = 0; k < 8; ++k) {
                const float2 tw = w[PADIDX(jo + k * 64)];
                f[k] = make_float2(f[k].x * tw.x - f[k].y * tw.y,
                                   f[k].x * tw.y + f[k].y * tw.x);
            }
        }
        // s=1: pairs (k,k+4), twidx = 2*jo + 128*k
        #pragma unroll
        for (int k = 0; k < 4; ++k) {
            const float2 tw = w[PADIDX(2 * jo + 128 * k)];
            BFLY(f[k], f[k + 4], tw);
        }
        // s=2: pairs (k,k+2), twidx = 4*jo (+256 for odd k-lower)
        {
            const float2 tw0 = w[PADIDX(4 * jo)];
            const float2 tw1 = w[PADIDX(4 * jo + 256)];
            BFLY(f[0], f[2], tw0); BFLY(f[1], f[3], tw1);
            BFLY(f[4], f[6], tw0); BFLY(f[5], f[7], tw1);
        }
        // s=3: pairs (k,k+1), twidx = 8*jo
        {
            const float2 tw = w[PADIDX(8 * jo)];
            BFLY(f[0], f[1], tw); BFLY(f[2], f[3], tw);
            BFLY(f[4], f[5], tw); BFLY(f[6], f[7], tw);
        }
        #pragma unroll
        for (int k = 0; k < 8; ++k)
            g[arr][PADIDX(hh * 512 + jo + k * 64)] = f[k];
    }
    // wave-private array: no barrier needed (same-wave LDS program order)

    // ---- Pass B: levels s=4..6, octets at stride 8 within each 64-block.
    #pragma unroll
    for (int q = 0; q < 2; ++q) {
        const int arr = wv;
        const int b64 = q * 8 + (lane >> 3);   // 0..15
        const int jo  = lane & 7;              // 0..7
        const int e0  = b64 * 64 + jo;
        float2 f[8];
        #pragma unroll
        for (int k = 0; k < 8; ++k)
            f[k] = g[arr][PADIDX(e0 + 8 * k)];
        // s=4: pairs (k,k+4), twidx = 16*jo + 128*k
        #pragma unroll
        for (int k = 0; k < 4; ++k) {
            const float2 tw = w[PADIDX(16 * jo + 128 * k)];
            BFLY(f[k], f[k + 4], tw);
        }
        // s=5: pairs (k,k+2), twidx = 32*jo (+256)
        {
            const float2 tw0 = w[PADIDX(32 * jo)];
            const float2 tw1 = w[PADIDX(32 * jo + 256)];
            BFLY(f[0], f[2], tw0); BFLY(f[1], f[3], tw1);
            BFLY(f[4], f[6], tw0); BFLY(f[5], f[7], tw1);
        }
        // s=6: pairs (k,k+1), twidx = 64*jo
        {
            const float2 tw = w[PADIDX(64 * jo)];
            BFLY(f[0], f[1], tw); BFLY(f[2], f[3], tw);
            BFLY(f[4], f[5], tw); BFLY(f[6], f[7], tw);
        }
        #pragma unroll
        for (int k = 0; k < 8; ++k)
            g[arr][PADIDX(e0 + 8 * k)] = f[k];
    }
    // wave-private array: no barrier needed

    // ---- Pass C: levels s=7..9, consecutive 8-blocks. Level 9 keeps only
    // even positions (odd outputs are never read by the divide).
    #pragma unroll
    for (int q = 0; q < 2; ++q) {
        const int arr = wv;
        const int b8  = q * 64 + lane;       // 0..127
        const int e0  = b8 * 8;
        float2 f[8];
        #pragma unroll
        for (int k = 0; k < 8; ++k)
            f[k] = g[arr][PADIDX(e0 + k)];
        // s=7: pairs (k,k+4), twidx = 128*k
        BFLY(f[0], f[4], w[PADIDX(0)]);
        BFLY(f[1], f[5], w[PADIDX(128)]);
        BFLY(f[2], f[6], w[PADIDX(256)]);
        BFLY(f[3], f[7], w[PADIDX(384)]);
        // s=8: pairs (k,k+2), twidx = 256*(k&1)
        {
            const float2 tw0 = w[PADIDX(0)];
            const float2 tw1 = w[PADIDX(256)];
            BFLY(f[0], f[2], tw0); BFLY(f[1], f[3], tw1);
            BFLY(f[4], f[6], tw0); BFLY(f[5], f[7], tw1);
        }
        // s=9: evens only: f[k] += f[k+1]
        f[0].x += f[1].x; f[0].y += f[1].y;
        f[2].x += f[3].x; f[2].y += f[3].y;
        f[4].x += f[5].x; f[4].y += f[5].y;
        f[6].x += f[7].x; f[6].y += f[7].y;
        g[arr][PADIDX(e0 + 0)] = f[0];
        g[arr][PADIDX(e0 + 2)] = f[2];
        g[arr][PADIDX(e0 + 4)] = f[4];
        g[arr][PADIDX(e0 + 6)] = f[6];
    }
    __syncthreads();

    // even positions 2i hold mu = bitrev9(i). Divide both z and store float4.
    for (int e2 = t; e2 < 512; e2 += 256) {
        const int i  = e2;
        const int pi = PADIDX(2 * i);
        const int mu = (int)(__brev((unsigned)i) >> 23);   // bitrev9
        float4 res;
        #pragma unroll
        for (int zi = 0; zi < 2; ++zi) {
            const float2 D  = g[zi][pi];
            const float2 Nm = g[2 + zi][pi];
            const float inv = 1.f / (D.x * D.x + D.y * D.y);
            const float rr = (Nm.x * D.x + Nm.y * D.y) * inv;
            const float ri = (Nm.y * D.x - Nm.x * D.y) * inv;
            if (zi == 0) { res.x = rr; res.y = ri; }
            else         { res.z = rr; res.w = ri; }
        }
        const size_t o = ((size_t)be * NPOS + mu) * 64 + zg * 2;
        if (out_cplx) {
            *(float4*)&((float2*)out)[o] = res;
        } else {
            out[o]     = res.x;
            out[o + 1] = res.z;
        }
    }
}

// ---------------- small-ws fallback: fp32 GEMM + fp64 mdft ------------------
__global__ __launch_bounds__(256)
void gemm_kv_kernel(const float* __restrict__ x,
                    const float* __restrict__ Wk,
                    const float* __restrict__ Wv,
                    float* __restrict__ K,
                    float* __restrict__ V,
                    float* __restrict__ partials)
{
    const int blk  = blockIdx.x;
    const int sel  = (blk >> 2) & 1;
    const int cg2  = blk & 3;
    const int rt   = blk >> 3;
    const int row0 = rt * 16;
    const int col0 = cg2 * 128;
    const int t    = threadIdx.x;
    const int tc   = t & 31;
    const int tr   = t >> 5;
    const float* __restrict__ W   = sel ? Wv : Wk;
    float* __restrict__       Out = sel ? V  : K;

    __shared__ float xs[16][DIMX];
    __shared__ float red[4];

    #pragma unroll
    for (int jj = 0; jj < 8; ++jj) {
        const int f = t + jj * 256;
        const int row = f >> 7, c4 = f & 127;
        *(float4*)&xs[row][c4 * 4] = *(const float4*)&x[(size_t)(row0 + row) * DIMX + c4 * 4];
    }
    __syncthreads();

    const float* Wb = W + col0 + tc * 4;
    float4 wA[8], wB[8];
    #pragma unroll
    for (int jj = 0; jj < 8; ++jj) wA[jj] = *(const float4*)&Wb[(size_t)(jj) * DIMX];
    #pragma unroll
    for (int jj = 0; jj < 8; ++jj) wB[jj] = *(const float4*)&Wb[(size_t)(8 + jj) * DIMX];

    float acc[2][4] = {{0,0,0,0},{0,0,0,0}};
    const int r0 = tr * 2;

    #define COMPUTE_CHUNK(WREG, CH)                                            \
        {   float4 xv0a = *(const float4*)&xs[r0][(CH) * 8];                   \
            float4 xv0b = *(const float4*)&xs[r0][(CH) * 8 + 4];               \
            float4 xv1a = *(const float4*)&xs[r0 + 1][(CH) * 8];               \
            float4 xv1b = *(const float4*)&xs[r0 + 1][(CH) * 8 + 4];           \
            _Pragma("unroll")                                                  \
            for (int kk = 0; kk < 4; ++kk) {                                   \
                const float x0 = (&xv0a.x)[kk], x1 = (&xv1a.x)[kk];            \
                _Pragma("unroll")                                              \
                for (int cc = 0; cc < 4; ++cc) {                               \
                    acc[0][cc] = fmaf(x0, (&WREG[kk].x)[cc], acc[0][cc]);      \
                    acc[1][cc] = fmaf(x1, (&WREG[kk].x)[cc], acc[1][cc]);      \
                } }                                                            \
            _Pragma("unroll")                                                  \
            for (int kk = 0; kk < 4; ++kk) {                                   \
                const float x0 = (&xv0b.x)[kk], x1 = (&xv1b.x)[kk];            \
                _Pragma("unroll")                                              \
                for (int cc = 0; cc < 4; ++cc) {                               \
                    acc[0][cc] = fmaf(x0, (&WREG[kk + 4].x)[cc], acc[0][cc]);  \
                    acc[1][cc] = fmaf(x1, (&WREG[kk + 4].x)[cc], acc[1][cc]);  \
                } } }

    for (int ch = 0; ch < 64; ch += 2) {
        COMPUTE_CHUNK(wA, ch)
        if (ch < 62) {
            #pragma unroll
            for (int jj = 0; jj < 8; ++jj)
                wA[jj] = *(const float4*)&Wb[(size_t)((ch + 2) * 8 + jj) * DIMX];
        }
        COMPUTE_CHUNK(wB, ch + 1)
        if (ch < 62) {
            #pragma unroll
            for (int jj = 0; jj < 8; ++jj)
                wB[jj] = *(const float4*)&Wb[(size_t)((ch + 3) * 8 + jj) * DIMX];
        }
    }
    #undef COMPUTE_CHUNK

    float ss = 0.f;
    #pragma unroll
    for (int i = 0; i < 2; ++i) {
        const int row = row0 + r0 + i;
        const float4 o = make_float4(acc[i][0], acc[i][1], acc[i][2], acc[i][3]);
        *(float4*)&Out[(size_t)row * DIMX + col0 + tc * 4] = o;
        ss += o.x * o.x + o.y * o.y + o.z * o.z + o.w * o.w;
    }
    if (sel == 0) {
        #pragma unroll
        for (int off = 32; off > 0; off >>= 1)
            ss += __shfl_down(ss, off, 64);
        if ((t & 63) == 0) red[t >> 6] = ss;
        __syncthreads();
        if (t == 0) partials[blk] = red[0] + red[1] + red[2] + red[3];
    } else {
        if (t == 0) partials[blk] = 0.f;
    }
}

__global__ __launch_bounds__(256)
void mdft_fallback_kernel(const float2* __restrict__ Gk,
                          const float2* __restrict__ Gp,
                          float* __restrict__ out,
                          int out_cplx)
{
    const int blk = blockIdx.x;
    const int be = blk >> 6, z = blk & 63;
    const int t = threadIdx.x;
    __shared__ float2 gk[512];
    __shared__ float2 gp[512];
    __shared__ float2 w[1024];

    for (int m = t; m < 512; m += 256) {
        const size_t idx = ((size_t)be * NPOS + m) * 64 + z;
        gk[m] = Gk[idx];
        gp[m] = Gp[idx];
    }
    for (int jj = t; jj < 1024; jj += 256) {
        double s, c;
        sincos(-6.2831853071795864769 * (double)jj / 1024.0, &s, &c);
        w[jj] = make_float2((float)c, (float)s);
    }
    __syncthreads();

    #pragma unroll
    for (int half = 0; half < 2; ++half) {
        const int mu = t + half * 256;
        double dr = 0.0, di = 0.0, nr = 0.0, ni = 0.0;
        int idx = 0;
        for (int m = 0; m < 512; ++m) {
            const float2 tw = w[idx];
            idx = (idx + mu) & 1023;
            const float2 a = gk[m];
            dr += (double)(a.x * tw.x - a.y * tw.y);
            di += (double)(a.x * tw.y + a.y * tw.x);
            const float2 p2 = gp[m];
            nr += (double)(p2.x * tw.x - p2.y * tw.y);
            ni += (double)(p2.x * tw.y + p2.y * tw.x);
        }
        const double dmag = dr * dr + di * di;
        const double orr = (nr * dr + ni * di) / dmag;
        const double oii = (ni * dr - nr * di) / dmag;
        const size_t o = ((size_t)be * NPOS + mu) * 64 + z;
        if (out_cplx) {
            out[2 * o]     = (float)orr;
            out[2 * o + 1] = (float)oii;
        } else {
            out[o] = (float)orr;
        }
    }
}

extern "C" void kernel_launch(void* const* d_in, const int* in_sizes, int n_in,
                              void* d_out, int out_size, void* d_ws, size_t ws_size,
                              hipStream_t stream)
{
    // inputs: x, Wq, Wk, Wv, Er — only x, Wk, Wv needed
    const float* x  = (const float*)d_in[0];
    const float* Wk = (const float*)d_in[2];
    const float* Wv = (const float*)d_in[3];
    float* out = (float*)d_out;

    char* ws = (char*)d_ws;
    float*  K    = (float*)(ws);                           // 2 MB
    float*  V    = (float*)(ws + (size_t)2097152);         // 2 MB
    float2* Gk   = (float2*)(ws + (size_t)4194304);        // 4 MB
    float*  part = (float*)(ws + (size_t)8388608);         // 2 KB (512 floats)
    const int out_cplx = (out_size >= 2 * 2 * 8 * 512 * 64) ? 1 : 0;

    const bool ws_big = (ws_size >= (size_t)20971520);     // needs 20 MB
    float2* Gp = ws_big ? (float2*)(ws + (size_t)8390656)  // 4 MB
                        : (float2*)d_out;                  // alias-safe fallback

    if (ws_big) {
        ushort_t* xh  = (ushort_t*)(ws + (size_t)16777216);  // 1 MB each
        ushort_t* xl  = (ushort_t*)(ws + (size_t)17825792);
        ushort_t* wth = (ushort_t*)(ws + (size_t)18874368);
        ushort_t* wtl = (ushort_t*)(ws + (size_t)19922944);
        float2*   twd = (float2*)(ws + (size_t)12584960);    // 4 KB (hole after Gp)
        hipLaunchKernelGGL(conv_kernel, dim3(1026), dim3(256), 0, stream,
                           x, Wk, Wv, xh, xl, wth, wtl, twd);
        hipLaunchKernelGGL(gemm_mfma_kernel, dim3(512), dim3(256), 0, stream,
                           xh, xl, wth, wtl, K, V, part);
        hipLaunchKernelGGL(stage1_kernel, dim3(512), dim3(256), 0, stream,
                           K, V, part, Gk, Gp);
        hipLaunchKernelGGL(fft_div_kernel, dim3(512), dim3(256), 0, stream,
                           Gk, Gp, twd, out, out_cplx);
    } else {
        hipLaunchKernelGGL(gemm_kv_kernel, dim3(512), dim3(256), 0, stream,
                           x, Wk, Wv, K, V, part);
        hipLaunchKernelGGL(stage1_kernel, dim3(512), dim3(256), 0, stream,
                           K, V, part, Gk, Gp);
        hipLaunchKernelGGL(mdft_fallback_kernel, dim3(1024), dim3(256), 0, stream,
                           Gk, Gp, out, out_cplx);
    }
}

// Round 7
// 99.048 us; speedup vs baseline: 1.0984x; 1.0001x over previous
//
#include <hip/hip_runtime.h>
#include <math.h>

// B=2, N=512, DIM=512, HEADS=8, DIM_HEAD=64
// out[be,mu,z] = FFT1024(S_k*v)[mu] / FFT1024(k_)[mu],  mu in [0,512)
// after a 2x8 (b,h)-DFT; inputs zero-padded 512 -> 1024 on the m axis.
// Gk/Gp layout: [be][m][z] (z fastest) — PRODUCER-coalesced. R16 tried
// [be][z][m] (consumer-coalesced): +8.7us REGRESSION — m is stage1's
// blockIdx, so each 64B line got 8B fragments from 8 different workgroups
// (cross-XCD false sharing, partial-line RFO). Scatter must live on the
// READ side. Do not revisit.
// GEMM path: split-bf16 MFMA (x=xh+xl, W=wh+wl; 3 MFMAs; residual ~2^-17).
// R12: fft as 3 register-fused radix-8 passes; twiddles hoisted to conv.
// R14: barrier-free FFT passes; sk folded into DFT; ushort4 conv stores.
// R15: gemm LDS-staged B via global_load_lds (dbuf, BK=64) -> -5.3us.
// R17: gemm A-operand register prefetch -> -1.0us.
// R18 (this): conv x-split pass DELETED — xh+xl (4B) == fp32 (4B), so gemm
// reads x fp32 directly and splits in-register with native bf16 casts
// (l = rne(x-h) captures the residual exactly -> error stays at the split's
// ~2^-17 scale). conv shrinks 1026 -> 514 blocks (W transpose + twd only).

#define DIMX 512
#define NPOS 512
#define PADIDX(m) ((m) + ((m) >> 4))

typedef unsigned short ushort_t;
typedef unsigned int uint_t;
typedef __bf16 bf16x8 __attribute__((ext_vector_type(8)));
typedef float floatx4 __attribute__((ext_vector_type(4)));

static __device__ inline ushort_t f2bf(float f) {
    uint_t u = __float_as_uint(f);
    u = u + 0x7FFFu + ((u >> 16) & 1u);      // round-to-nearest-even
    return (ushort_t)(u >> 16);
}
static __device__ inline float bf2f(ushort_t h) {
    return __uint_as_float(((uint_t)h) << 16);
}

// split 8 fp32 (two float4) into high/low bf16x8 fragments, in-register.
static __device__ inline void cvt_split8(const float4 a, const float4 b,
                                         bf16x8& h, bf16x8& l) {
    const float f8[8] = {a.x, a.y, a.z, a.w, b.x, b.y, b.z, b.w};
    #pragma unroll
    for (int i = 0; i < 8; ++i) {
        const __bf16 hb = (__bf16)f8[i];
        h[i] = hb;
        l[i] = (__bf16)(f8[i] - (float)hb);
    }
}

// butterfly: lo' = lo+hi; hi' = (lo-hi)*tw   (same op order as the original)
#define BFLY(lo, hi, tw) do {                                   \
    const float sr_ = (lo).x - (hi).x, si_ = (lo).y - (hi).y;   \
    (lo).x += (hi).x; (lo).y += (hi).y;                         \
    (hi).x = sr_ * (tw).x - si_ * (tw).y;                       \
    (hi).y = sr_ * (tw).y + si_ * (tw).x;                       \
} while (0)

// ---------------- conv: blk<512 -> W split+T; blk>=512 -> FFT twiddle table -
__global__ __launch_bounds__(256)
void conv_kernel(const float* __restrict__ Wk, const float* __restrict__ Wv,
                 ushort_t* __restrict__ wth, ushort_t* __restrict__ wtl,
                 float2* __restrict__ twd)
{
    const int blk = blockIdx.x;
    const int t = threadIdx.x;
    if (blk < 512) {
        // Wk|Wv [k][n] -> wth/wtl [n][k] split bf16, 32x32 LDS transpose
        __shared__ float tile[32][33];
        const int b2 = blk;
        const int s  = b2 >> 8;            // 0=Wk, 1=Wv
        const int kt = (b2 >> 4) & 15;
        const int nt = b2 & 15;
        const int c  = t & 31, r4 = t >> 5;
        const float* __restrict__ W = s ? Wv : Wk;
        #pragma unroll
        for (int i = 0; i < 4; ++i) {
            const int row = r4 + i * 8;
            tile[row][c] = W[(size_t)(kt * 32 + row) * 512 + nt * 32 + c];
        }
        __syncthreads();
        #pragma unroll
        for (int i = 0; i < 4; ++i) {
            const int nl = r4 + i * 8;
            const float v = tile[c][nl];           // = W[kt*32+c][nt*32+nl]
            const ushort_t h = f2bf(v);
            const ushort_t l = f2bf(v - bf2f(h));
            const size_t o = (size_t)(s * 512 + nt * 32 + nl) * 512 + kt * 32 + c;
            wth[o] = h;
            wtl[o] = l;
        }
    } else {
        // twiddle table: exp(-2*pi*i*j/1024), j in [0,512)
        const int jj = (blk - 512) * 256 + t;
        double s, cc;
        sincos(-6.2831853071795864769 * (double)jj / 1024.0, &s, &cc);
        twd[jj] = make_float2((float)cc, (float)s);
    }
}

// ---------------- GEMM: split-bf16 MFMA, LDS-staged B (global_load_lds) -----
// grid 512: ct = blk>>5 (16 col-tiles of 64), rt = blk&31 (32 row-tiles of 32);
// Wave w: rows rt*32+(w&1)*16, cols ct*64+(w>>1)*32 (2 col-frags) -> each B
// element staged ONCE per block. A read as fp32 from x (same bytes as the
// old xh+xl pair) and split in-register (R18); register-prefetched one
// K-step ahead (R17) so loads issue under the MFMA phase.
// B LDS layout [arr][kq=8][n=64][8 bf16]: gload_lds dest linear in lane order
// (m104); frag ds_read_b128 at n-stride 16 B -> 2-way bank alias (free, m136).
__global__ __launch_bounds__(256)
void gemm_mfma_kernel(const float* __restrict__ x,
                      const ushort_t* __restrict__ wth, const ushort_t* __restrict__ wtl,
                      float* __restrict__ K, float* __restrict__ V,
                      float* __restrict__ partials)
{
    const int blk = blockIdx.x;       // 0..511
    const int ct = blk >> 5;          // 0..15
    const int rt = blk & 31;          // 0..31
    const int t = threadIdx.x;
    const int w = t >> 6, lane = t & 63;
    const int qd = lane >> 4, lm = lane & 15;

    const int mrow = rt * 32 + (w & 1) * 16 + lm;
    const int wcol = (w >> 1) * 32;                 // 0 or 32 within the 64-col tile
    const size_t aoff = (size_t)mrow * 512 + qd * 8;   // float index into x

    __shared__ __align__(16) ushort_t Bs[2][2][8][64][8];   // [buf][arr][kq][n][8k] = 32 KB
    __shared__ float red[4];

    // stage one BK=64 slab (16 KB) of B into LDS buffer `buf`:
    // 16 segments (arr x kq), 4 per wave; per segment: 64 lanes x 16 B, lane = n.
    #define STAGE(buf_, k0_)                                                     \
    {                                                                            \
        _Pragma("unroll")                                                        \
        for (int i = 0; i < 4; ++i) {                                            \
            const int seg = w * 4 + i;                                           \
            const int arr_ = seg >> 3, kq_ = seg & 7;                            \
            const ushort_t* src_ = (arr_ ? wtl : wth)                            \
                + (size_t)(ct * 64 + lane) * 512 + (k0_) + kq_ * 8;              \
            __builtin_amdgcn_global_load_lds(                                    \
                (const __attribute__((address_space(1))) uint_t*)src_,           \
                (__attribute__((address_space(3))) uint_t*)&Bs[buf_][arr_][kq_][0][0], \
                16, 0, 0);                                                       \
        }                                                                        \
    }

    floatx4 acc0 = {0.f, 0.f, 0.f, 0.f};
    floatx4 acc1 = {0.f, 0.f, 0.f, 0.f};

    // A register prefetch (current K-step fp32 operands, 4 x float4 = 64 B)
    float4 cA0 = *(const float4*)&x[aoff];
    float4 cA1 = *(const float4*)&x[aoff + 4];
    float4 cA2 = *(const float4*)&x[aoff + 32];
    float4 cA3 = *(const float4*)&x[aoff + 36];

    STAGE(0, 0)
    for (int ks = 0; ks < 8; ++ks) {
        __syncthreads();                       // drains gload_lds of buf[ks]
        const int buf = ks & 1;
        const int k0 = ks * 64;
        if (ks < 7) STAGE(buf ^ 1, k0 + 64)    // prefetch next slab async

        // issue next-step A loads now; consumed only after the next barrier
        const size_t anext = aoff + (size_t)(ks < 7 ? k0 + 64 : 0);
        const float4 nA0 = *(const float4*)&x[anext];
        const float4 nA1 = *(const float4*)&x[anext + 4];
        const float4 nA2 = *(const float4*)&x[anext + 32];
        const float4 nA3 = *(const float4*)&x[anext + 36];

        // in-register split of the current A operands (VALU, overlaps MFMA pipe)
        bf16x8 Ah0, Al0, Ah1, Al1;
        cvt_split8(cA0, cA1, Ah0, Al0);
        cvt_split8(cA2, cA3, Ah1, Al1);

        // s2 = 0 (kq = qd)
        {
            const bf16x8 B0h = *(const bf16x8*)Bs[buf][0][qd][wcol + lm];
            const bf16x8 B0l = *(const bf16x8*)Bs[buf][1][qd][wcol + lm];
            const bf16x8 B1h = *(const bf16x8*)Bs[buf][0][qd][wcol + 16 + lm];
            const bf16x8 B1l = *(const bf16x8*)Bs[buf][1][qd][wcol + 16 + lm];
            acc0 = __builtin_amdgcn_mfma_f32_16x16x32_bf16(Ah0, B0h, acc0, 0, 0, 0);
            acc0 = __builtin_amdgcn_mfma_f32_16x16x32_bf16(Ah0, B0l, acc0, 0, 0, 0);
            acc0 = __builtin_amdgcn_mfma_f32_16x16x32_bf16(Al0, B0h, acc0, 0, 0, 0);
            acc1 = __builtin_amdgcn_mfma_f32_16x16x32_bf16(Ah0, B1h, acc1, 0, 0, 0);
            acc1 = __builtin_amdgcn_mfma_f32_16x16x32_bf16(Ah0, B1l, acc1, 0, 0, 0);
            acc1 = __builtin_amdgcn_mfma_f32_16x16x32_bf16(Al0, B1h, acc1, 0, 0, 0);
        }
        // s2 = 1 (kq = qd + 4)
        {
            const int kq = qd + 4;
            const bf16x8 B0h = *(const bf16x8*)Bs[buf][0][kq][wcol + lm];
            const bf16x8 B0l = *(const bf16x8*)Bs[buf][1][kq][wcol + lm];
            const bf16x8 B1h = *(const bf16x8*)Bs[buf][0][kq][wcol + 16 + lm];
            const bf16x8 B1l = *(const bf16x8*)Bs[buf][1][kq][wcol + 16 + lm];
            acc0 = __builtin_amdgcn_mfma_f32_16x16x32_bf16(Ah1, B0h, acc0, 0, 0, 0);
            acc0 = __builtin_amdgcn_mfma_f32_16x16x32_bf16(Ah1, B0l, acc0, 0, 0, 0);
            acc0 = __builtin_amdgcn_mfma_f32_16x16x32_bf16(Al1, B0h, acc0, 0, 0, 0);
            acc1 = __builtin_amdgcn_mfma_f32_16x16x32_bf16(Ah1, B1h, acc1, 0, 0, 0);
            acc1 = __builtin_amdgcn_mfma_f32_16x16x32_bf16(Ah1, B1l, acc1, 0, 0, 0);
            acc1 = __builtin_amdgcn_mfma_f32_16x16x32_bf16(Al1, B1h, acc1, 0, 0, 0);
        }
        cA0 = nA0; cA1 = nA1; cA2 = nA2; cA3 = nA3;
    }
    #undef STAGE

    // epilogue: D[row=quad*4+r][col=lane&15]
    float ss = 0.f;
    const int orow0 = rt * 32 + (w & 1) * 16 + qd * 4;
    float* __restrict__ O = (ct < 8) ? K : V;
    const int cb = (ct < 8) ? 0 : 512;
    const int c0 = ct * 64 + wcol + lm - cb;
    #pragma unroll
    for (int r = 0; r < 4; ++r) {
        const size_t row = orow0 + r;
        const float v0 = acc0[r], v1 = acc1[r];
        O[row * 512 + c0]      = v0;
        O[row * 512 + c0 + 16] = v1;
        if (ct < 8) ss += v0 * v0 + v1 * v1;
    }
    #pragma unroll
    for (int off = 32; off > 0; off >>= 1)
        ss += __shfl_down(ss, off, 64);
    if (lane == 0) red[w] = ss;
    __syncthreads();
    if (t == 0) partials[blk] = red[0] + red[1] + red[2] + red[3];
}

// 8-point DFT twiddles: exp(-2*pi*i*k/8)
__device__ __constant__ float C8[8] = {
    1.f, 0.70710678118654752440f, 0.f, -0.70710678118654752440f,
   -1.f, -0.70710678118654752440f, 0.f, 0.70710678118654752440f };
__device__ __constant__ float S8[8] = {
    0.f, -0.70710678118654752440f, -1.f, -0.70710678118654752440f,
    0.f,  0.70710678118654752440f,  1.f,  0.70710678118654752440f };

// elu(K/norm), S_k, P = S_k*V, 2x8 (b,h)-DFT. Writes [be][m][z], float4
// (producer-coalesced full-line stores; consumer scatter is the cheap side).
__global__ __launch_bounds__(256)
void stage1_kernel(const float* __restrict__ K,
                   const float* __restrict__ V,
                   const float* __restrict__ partials,
                   float2* __restrict__ Gk,
                   float2* __restrict__ Gp)
{
    const int m = blockIdx.x;     // 0..511
    const int t = threadIdx.x;
    __shared__ float kk[2][8][64];
    __shared__ float pp[2][8][64];
    __shared__ float skp[16][4];
    __shared__ float sk[2][8];
    __shared__ float sred[4];

    // reduce the 512 gemm partials -> global Frobenius scale
    float p = partials[t] + partials[t + 256];
    #pragma unroll
    for (int off = 32; off > 0; off >>= 1)
        p += __shfl_down(p, off, 64);
    if ((t & 63) == 0) sred[t >> 6] = p;
    __syncthreads();
    const float scale = (float)(1.0 / sqrt((double)sred[0] + (double)sred[1] +
                                           (double)sred[2] + (double)sred[3]));

    // float4 loads: thread t covers elements 4t..4t+3 (4 consecutive z)
    {
        const int e0 = t * 4;
        const int b = e0 >> 9, rem = e0 & 511, h = rem >> 6, z = rem & 63;
        const size_t src = (size_t)(b * 512 + m) * DIMX + h * 64 + z;
        const float4 kv4 = *(const float4*)&K[src];
        const float4 vv4 = *(const float4*)&V[src];
        const float kf[4] = {kv4.x, kv4.y, kv4.z, kv4.w};
        const float vf[4] = {vv4.x, vv4.y, vv4.z, vv4.w};
        #pragma unroll
        for (int e = 0; e < 4; ++e) {
            const float kv = kf[e] * scale;
            kk[b][h][z + e] = kv > 0.f ? kv : expm1f(kv);
            pp[b][h][z + e] = vf[e];
        }
    }
    __syncthreads();
    if (t < 64) {               // sk[b][h] = sum_z elu(k): 4 threads per (b,h)
        const int bh = t >> 2, q = t & 3;
        float s = 0.f;
        #pragma unroll
        for (int zz = 0; zz < 16; ++zz) s += kk[bh >> 3][bh & 7][q * 16 + zz];
        skp[bh][q] = s;
    }
    __syncthreads();
    if (t < 16) sk[t >> 3][t & 7] = skp[t][0] + skp[t][1] + skp[t][2] + skp[t][3];
    __syncthreads();

    // 2x8 (b,h)-DFT with folded sk; each thread computes a z-PAIR -> float4.
    for (int e2 = t; e2 < 512; e2 += 256) {
        const int be = e2 >> 5;          // 0..15
        const int zp = e2 & 31;          // z pair index
        const int beta = be >> 3, eta = be & 7;
        float kr[2] = {0.f, 0.f}, ki[2] = {0.f, 0.f};
        float pr[2] = {0.f, 0.f}, pim[2] = {0.f, 0.f};
        #pragma unroll
        for (int b = 0; b < 2; ++b) {
            const float sgn = (beta & b) ? -1.f : 1.f;
            #pragma unroll
            for (int h = 0; h < 8; ++h) {
                const int ph = (eta * h) & 7;
                const float cr = C8[ph], ci = S8[ph];
                const float skv = sk[b][h];
                #pragma unroll
                for (int zz = 0; zz < 2; ++zz) {
                    const int z = zp * 2 + zz;
                    const float a = kk[b][h][z] * sgn;
                    kr[zz] = fmaf(a, cr, kr[zz]);
                    ki[zz] = fmaf(a, ci, ki[zz]);
                    const float p2 = (pp[b][h][z] * skv) * sgn;
                    pr[zz]  = fmaf(p2, cr, pr[zz]);
                    pim[zz] = fmaf(p2, ci, pim[zz]);
                }
            }
        }
        const float4 rk = make_float4(kr[0], ki[0], kr[1], ki[1]);
        const float4 rp = make_float4(pr[0], pim[0], pr[1], pim[1]);
        const size_t o = ((size_t)be * NPOS + m) * 64 + zp * 2;
        *(float4*)&Gk[o] = rk;
        *(float4*)&Gp[o] = rp;
    }
}

// ---------------- Zero-padded 1024-pt FFT (3 radix-8 passes) + divide -------
// Swizzle: blk = be*32 + l*8 + j, zg = j*4 + l  ->  the 4 blocks sharing each
// 64B out-line / Gk-line (zg group of 4, fixed be) have equal blk%8 (same XCD).
// Zero-pad upper half not materialized; stage-0 twist fused into Pass A upper
// octet. FFT arrays wave-private between input and divide -> no mid barriers.
__global__ __launch_bounds__(256)
void fft_div_kernel(const float2* __restrict__ Gk,   // [be][m][z]
                    const float2* __restrict__ Gp,
                    const float2* __restrict__ twd,  // 512 twiddles (from conv)
                    float* __restrict__ out, int out_cplx)
{
    const int blk = blockIdx.x;
    const int j  = blk & 7;
    const int l  = (blk >> 3) & 3;
    const int be = blk >> 5;
    const int zg = j * 4 + l;            // z = 2*zg, 2*zg+1
    const int t  = threadIdx.x;

    __shared__ float2 g[4][1088];   // arr = a*2+zi, padded 1024 -> 1088
    __shared__ float2 w[544];       // padded 512 twiddles

    // twiddle load + raw input load (lower 512 only), ONE barrier
    for (int jj = t; jj < 512; jj += 256)
        w[PADIDX(jj)] = twd[jj];
    for (int e = t; e < 1024; e += 256) {
        const int a = e >> 9;            // 0 -> Gk, 1 -> Gp
        const int m = e & 511;
        const float4 v4 = *(const float4*)&(a ? Gp : Gk)[((size_t)be * NPOS + m) * 64 + zg * 2];
        g[a * 2 + 0][PADIDX(m)] = make_float2(v4.x, v4.y);
        g[a * 2 + 1][PADIDX(m)] = make_float2(v4.z, v4.w);
    }
    __syncthreads();

    const int wv   = t >> 6;
    const int lane = t & 63;

    // ---- Pass A: levels s=1..3, octets at stride 64 within each 512-half.
    // qh=0 -> upper half (reads lower raw + stage-0 twist), qh=1 -> lower.
    #pragma unroll
    for (int qh = 0; qh < 2; ++qh) {
        const int hh  = 1 - qh;
        const int arr = wv;
        const int jo  = lane;                // 0..63
        float2 f[8];
        #pragma unroll
        for (int k = 0; k < 8; ++k)
            f[k] = g[arr][PADIDX(jo + k * 64)];          // lower half (raw)
        if (hh == 1) {                                   // fused stage-0 twist
            #pragma unroll
            for (int k = 0; k < 8; ++k) {
                const float2 tw = w[PADIDX(jo + k * 64)];
                f[k] = make_float2(f[k].x * tw.x - f[k].y * tw.y,
                                   f[k].x * tw.y + f[k].y * tw.x);
            }
        }
        // s=1: pairs (k,k+4), twidx = 2*jo + 128*k
        #pragma unroll
        for (int k = 0; k < 4; ++k) {
            const float2 tw = w[PADIDX(2 * jo + 128 * k)];
            BFLY(f[k], f[k + 4], tw);
        }
        // s=2: pairs (k,k+2), twidx = 4*jo (+256 for odd k-lower)
        {
            const float2 tw0 = w[PADIDX(4 * jo)];
            const float2 tw1 = w[PADIDX(4 * jo + 256)];
            BFLY(f[0], f[2], tw0); BFLY(f[1], f[3], tw1);
            BFLY(f[4], f[6], tw0); BFLY(f[5], f[7], tw1);
        }
        // s=3: pairs (k,k+1), twidx = 8*jo
        {
            const float2 tw = w[PADIDX(8 * jo)];
            BFLY(f[0], f[1], tw); BFLY(f[2], f[3], tw);
            BFLY(f[4], f[5], tw); BFLY(f[6], f[7], tw);
        }
        #pragma unroll
        for (int k = 0; k < 8; ++k)
            g[arr][PADIDX(hh * 512 + jo + k * 64)] = f[k];
    }
    // wave-private array: no barrier needed (same-wave LDS program order)

    // ---- Pass B: levels s=4..6, octets at stride 8 within each 64-block.
    #pragma unroll
    for (int q = 0; q < 2; ++q) {
        const int arr = wv;
        const int b64 = q * 8 + (lane >> 3);   // 0..15
        const int jo  = lane & 7;              // 0..7
        const int e0  = b64 * 64 + jo;
        float2 f[8];
        #pragma unroll
        for (int k = 0; k < 8; ++k)
            f[k] = g[arr][PADIDX(e0 + 8 * k)];
        // s=4: pairs (k,k+4), twidx = 16*jo + 128*k
        #pragma unroll
        for (int k = 0; k < 4; ++k) {
            const float2 tw = w[PADIDX(16 * jo + 128 * k)];
            BFLY(f[k], f[k + 4], tw);
        }
        // s=5: pairs (k,k+2), twidx = 32*jo (+256)
        {
            const float2 tw0 = w[PADIDX(32 * jo)];
            const float2 tw1 = w[PADIDX(32 * jo + 256)];
            BFLY(f[0], f[2], tw0); BFLY(f[1], f[3], tw1);
            BFLY(f[4], f[6], tw0); BFLY(f[5], f[7], tw1);
        }
        // s=6: pairs (k,k+1), twidx = 64*jo
        {
            const float2 tw = w[PADIDX(64 * jo)];
            BFLY(f[0], f[1], tw); BFLY(f[2], f[3], tw);
            BFLY(f[4], f[5], tw); BFLY(f[6], f[7], tw);
        }
        #pragma unroll
        for (int k = 0; k < 8; ++k)
            g[arr][PADIDX(e0 + 8 * k)] = f[k];
    }
    // wave-private array: no barrier needed

    // ---- Pass C: levels s=7..9, consecutive 8-blocks. Level 9 keeps only
    // even positions (odd outputs are never read by the divide).
    #pragma unroll
    for (int q = 0; q < 2; ++q) {
        const int arr = wv;
        const int b8  = q * 64 + lane;       // 0..127
        const int e0  = b8 * 8;
        float2 f[8];
        #pragma unroll
        for (int k = 0; k < 8; ++k)
            f[k] = g[arr][PADIDX(e0 + k)];
        // s=7: pairs (k,k+4), twidx = 128*k
        BFLY(f[0], f[4], w[PADIDX(0)]);
        BFLY(f[1], f[5], w[PADIDX(128)]);
        BFLY(f[2], f[6], w[PADIDX(256)]);
        BFLY(f[3], f[7], w[PADIDX(384)]);
        // s=8: pairs (k,k+2), twidx = 256*(k&1)
        {
            const float2 tw0 = w[PADIDX(0)];
            const float2 tw1 = w[PADIDX(256)];
            BFLY(f[0], f[2], tw0); BFLY(f[1], f[3], tw1);
            BFLY(f[4], f[6], tw0); BFLY(f[5], f[7], tw1);
        }
        // s=9: evens only: f[k] += f[k+1]
        f[0].x += f[1].x; f[0].y += f[1].y;
        f[2].x += f[3].x; f[2].y += f[3].y;
        f[4].x += f[5].x; f[4].y += f[5].y;
        f[6].x += f[7].x; f[6].y += f[7].y;
        g[arr][PADIDX(e0 + 0)] = f[0];
        g[arr][PADIDX(e0 + 2)] = f[2];
        g[arr][PADIDX(e0 + 4)] = f[4];
        g[arr][PADIDX(e0 + 6)] = f[6];
    }
    __syncthreads();

    // even positions 2i hold mu = bitrev9(i). Divide both z and store float4.
    for (int e2 = t; e2 < 512; e2 += 256) {
        const int i  = e2;
        const int pi = PADIDX(2 * i);
        const int mu = (int)(__brev((unsigned)i) >> 23);   // bitrev9
        float4 res;
        #pragma unroll
        for (int zi = 0; zi < 2; ++zi) {
            const float2 D  = g[zi][pi];
            const float2 Nm = g[2 + zi][pi];
            const float inv = 1.f / (D.x * D.x + D.y * D.y);
            const float rr = (Nm.x * D.x + Nm.y * D.y) * inv;
            const float ri = (Nm.y * D.x - Nm.x * D.y) * inv;
            if (zi == 0) { res.x = rr; res.y = ri; }
            else         { res.z = rr; res.w = ri; }
        }
        const size_t o = ((size_t)be * NPOS + mu) * 64 + zg * 2;
        if (out_cplx) {
            *(float4*)&((float2*)out)[o] = res;
        } else {
            out[o]     = res.x;
            out[o + 1] = res.z;
        }
    }
}

// ---------------- small-ws fallback: fp32 GEMM + fp64 mdft ------------------
__global__ __launch_bounds__(256)
void gemm_kv_kernel(const float* __restrict__ x,
                    const float* __restrict__ Wk,
                    const float* __restrict__ Wv,
                    float* __restrict__ K,
                    float* __restrict__ V,
                    float* __restrict__ partials)
{
    const int blk  = blockIdx.x;
    const int sel  = (blk >> 2) & 1;
    const int cg2  = blk & 3;
    const int rt   = blk >> 3;
    const int row0 = rt * 16;
    const int col0 = cg2 * 128;
    const int t    = threadIdx.x;
    const int tc   = t & 31;
    const int tr   = t >> 5;
    const float* __restrict__ W   = sel ? Wv : Wk;
    float* __restrict__       Out = sel ? V  : K;

    __shared__ float xs[16][DIMX];
    __shared__ float red[4];

    #pragma unroll
    for (int jj = 0; jj < 8; ++jj) {
        const int f = t + jj * 256;
        const int row = f >> 7, c4 = f & 127;
        *(float4*)&xs[row][c4 * 4] = *(const float4*)&x[(size_t)(row0 + row) * DIMX + c4 * 4];
    }
    __syncthreads();

    const float* Wb = W + col0 + tc * 4;
    float4 wA[8], wB[8];
    #pragma unroll
    for (int jj = 0; jj < 8; ++jj) wA[jj] = *(const float4*)&Wb[(size_t)(jj) * DIMX];
    #pragma unroll
    for (int jj = 0; jj < 8; ++jj) wB[jj] = *(const float4*)&Wb[(size_t)(8 + jj) * DIMX];

    float acc[2][4] = {{0,0,0,0},{0,0,0,0}};
    const int r0 = tr * 2;

    #define COMPUTE_CHUNK(WREG, CH)                                            \
        {   float4 xv0a = *(const float4*)&xs[r0][(CH) * 8];                   \
            float4 xv0b = *(const float4*)&xs[r0][(CH) * 8 + 4];               \
            float4 xv1a = *(const float4*)&xs[r0 + 1][(CH) * 8];               \
            float4 xv1b = *(const float4*)&xs[r0 + 1][(CH) * 8 + 4];           \
            _Pragma("unroll")                                                  \
            for (int kk = 0; kk < 4; ++kk) {                                   \
                const float x0 = (&xv0a.x)[kk], x1 = (&xv1a.x)[kk];            \
                _Pragma("unroll")                                              \
                for (int cc = 0; cc < 4; ++cc) {                               \
                    acc[0][cc] = fmaf(x0, (&WREG[kk].x)[cc], acc[0][cc]);      \
                    acc[1][cc] = fmaf(x1, (&WREG[kk].x)[cc], acc[1][cc]);      \
                } }                                                            \
            _Pragma("unroll")                                                  \
            for (int kk = 0; kk < 4; ++kk) {                                   \
                const float x0 = (&xv0b.x)[kk], x1 = (&xv1b.x)[kk];            \
                _Pragma("unroll")                                              \
                for (int cc = 0; cc < 4; ++cc) {                               \
                    acc[0][cc] = fmaf(x0, (&WREG[kk + 4].x)[cc], acc[0][cc]);  \
                    acc[1][cc] = fmaf(x1, (&WREG[kk + 4].x)[cc], acc[1][cc]);  \
                } } }

    for (int ch = 0; ch < 64; ch += 2) {
        COMPUTE_CHUNK(wA, ch)
        if (ch < 62) {
            #pragma unroll
            for (int jj = 0; jj < 8; ++jj)
                wA[jj] = *(const float4*)&Wb[(size_t)((ch + 2) * 8 + jj) * DIMX];
        }
        COMPUTE_CHUNK(wB, ch + 1)
        if (ch < 62) {
            #pragma unroll
            for (int jj = 0; jj < 8; ++jj)
                wB[jj] = *(const float4*)&Wb[(size_t)((ch + 3) * 8 + jj) * DIMX];
        }
    }
    #undef COMPUTE_CHUNK

    float ss = 0.f;
    #pragma unroll
    for (int i = 0; i < 2; ++i) {
        const int row = row0 + r0 + i;
        const float4 o = make_float4(acc[i][0], acc[i][1], acc[i][2], acc[i][3]);
        *(float4*)&Out[(size_t)row * DIMX + col0 + tc * 4] = o;
        ss += o.x * o.x + o.y * o.y + o.z * o.z + o.w * o.w;
    }
    if (sel == 0) {
        #pragma unroll
        for (int off = 32; off > 0; off >>= 1)
            ss += __shfl_down(ss, off, 64);
        if ((t & 63) == 0) red[t >> 6] = ss;
        __syncthreads();
        if (t == 0) partials[blk] = red[0] + red[1] + red[2] + red[3];
    } else {
        if (t == 0) partials[blk] = 0.f;
    }
}

__global__ __launch_bounds__(256)
void mdft_fallback_kernel(const float2* __restrict__ Gk,
                          const float2* __restrict__ Gp,
                          float* __restrict__ out,
                          int out_cplx)
{
    const int blk = blockIdx.x;
    const int be = blk >> 6, z = blk & 63;
    const int t = threadIdx.x;
    __shared__ float2 gk[512];
    __shared__ float2 gp[512];
    __shared__ float2 w[1024];

    for (int m = t; m < 512; m += 256) {
        const size_t idx = ((size_t)be * NPOS + m) * 64 + z;
        gk[m] = Gk[idx];
        gp[m] = Gp[idx];
    }
    for (int jj = t; jj < 1024; jj += 256) {
        double s, c;
        sincos(-6.2831853071795864769 * (double)jj / 1024.0, &s, &c);
        w[jj] = make_float2((float)c, (float)s);
    }
    __syncthreads();

    #pragma unroll
    for (int half = 0; half < 2; ++half) {
        const int mu = t + half * 256;
        double dr = 0.0, di = 0.0, nr = 0.0, ni = 0.0;
        int idx = 0;
        for (int m = 0; m < 512; ++m) {
            const float2 tw = w[idx];
            idx = (idx + mu) & 1023;
            const float2 a = gk[m];
            dr += (double)(a.x * tw.x - a.y * tw.y);
            di += (double)(a.x * tw.y + a.y * tw.x);
            const float2 p2 = gp[m];
            nr += (double)(p2.x * tw.x - p2.y * tw.y);
            ni += (double)(p2.x * tw.y + p2.y * tw.x);
        }
        const double dmag = dr * dr + di * di;
        const double orr = (nr * dr + ni * di) / dmag;
        const double oii = (ni * dr - nr * di) / dmag;
        const size_t o = ((size_t)be * NPOS + mu) * 64 + z;
        if (out_cplx) {
            out[2 * o]     = (float)orr;
            out[2 * o + 1] = (float)oii;
        } else {
            out[o] = (float)orr;
        }
    }
}

extern "C" void kernel_launch(void* const* d_in, const int* in_sizes, int n_in,
                              void* d_out, int out_size, void* d_ws, size_t ws_size,
                              hipStream_t stream)
{
    // inputs: x, Wq, Wk, Wv, Er — only x, Wk, Wv needed
    const float* x  = (const float*)d_in[0];
    const float* Wk = (const float*)d_in[2];
    const float* Wv = (const float*)d_in[3];
    float* out = (float*)d_out;

    char* ws = (char*)d_ws;
    float*  K    = (float*)(ws);                           // 2 MB
    float*  V    = (float*)(ws + (size_t)2097152);         // 2 MB
    float2* Gk   = (float2*)(ws + (size_t)4194304);        // 4 MB
    float*  part = (float*)(ws + (size_t)8388608);         // 2 KB (512 floats)
    const int out_cplx = (out_size >= 2 * 2 * 8 * 512 * 64) ? 1 : 0;

    const bool ws_big = (ws_size >= (size_t)20971520);     // needs 20 MB
    float2* Gp = ws_big ? (float2*)(ws + (size_t)8390656)  // 4 MB
                        : (float2*)d_out;                  // alias-safe fallback

    if (ws_big) {
        ushort_t* wth = (ushort_t*)(ws + (size_t)18874368);  // 1 MB each
        ushort_t* wtl = (ushort_t*)(ws + (size_t)19922944);
        float2*   twd = (float2*)(ws + (size_t)12584960);    // 4 KB (hole after Gp)
        hipLaunchKernelGGL(conv_kernel, dim3(514), dim3(256), 0, stream,
                           Wk, Wv, wth, wtl, twd);
        hipLaunchKernelGGL(gemm_mfma_kernel, dim3(512), dim3(256), 0, stream,
                           x, wth, wtl, K, V, part);
        hipLaunchKernelGGL(stage1_kernel, dim3(512), dim3(256), 0, stream,
                           K, V, part, Gk, Gp);
        hipLaunchKernelGGL(fft_div_kernel, dim3(512), dim3(256), 0, stream,
                           Gk, Gp, twd, out, out_cplx);
    } else {
        hipLaunchKernelGGL(gemm_kv_kernel, dim3(512), dim3(256), 0, stream,
                           x, Wk, Wv, K, V, part);
        hipLaunchKernelGGL(stage1_kernel, dim3(512), dim3(256), 0, stream,
                           K, V, part, Gk, Gp);
        hipLaunchKernelGGL(mdft_fallback_kernel, dim3(1024), dim3(256), 0, stream,
                           Gk, Gp, out, out_cplx);
    }
}